// Round 1
// baseline (884.976 us; speedup 1.0000x reference)
//
#include <hip/hip_runtime.h>

#define BT 32768
#define TSEQ 128

constexpr float EPSF = 1.1920929e-07f;

__device__ __forceinline__ float sigm(float z) { return 1.f / (1.f + __expf(-z)); }

__device__ __forceinline__ float red64(float v) {
  v += __shfl_xor(v, 1);  v += __shfl_xor(v, 2);  v += __shfl_xor(v, 4);
  v += __shfl_xor(v, 8);  v += __shfl_xor(v, 16); v += __shfl_xor(v, 32);
  return v;
}
__device__ __forceinline__ float red16(float v) {
  v += __shfl_xor(v, 1); v += __shfl_xor(v, 2); v += __shfl_xor(v, 4); v += __shfl_xor(v, 8);
  return v;
}
__device__ __forceinline__ void fma4(float4& a, float s, const float4& b) {
  a.x = fmaf(s, b.x, a.x); a.y = fmaf(s, b.y, a.y);
  a.z = fmaf(s, b.z, a.z); a.w = fmaf(s, b.w, a.w);
}
__device__ __forceinline__ float dot4(const float4& a, const float4& b, float acc) {
  acc = fmaf(a.x, b.x, acc); acc = fmaf(a.y, b.y, acc);
  acc = fmaf(a.z, b.z, acc); acc = fmaf(a.w, b.w, acc);
  return acc;
}

// ---------------------------------------------------------------------------
// engram GEMM: fused ngram-hash + embedding gather + [val_w | key_w] matmul.
// Tile: 64 tokens x 64 cols, K=256 in chunks of 32. A staged k-major in LDS.
// blockIdx.y = col tile: 0..1 -> v_base (w/ val_b), 2..9 -> k_raw.
// ---------------------------------------------------------------------------
__global__ __launch_bounds__(256) void eng_gemm(
    const int* __restrict__ ids, const int* __restrict__ mults,
    const float* __restrict__ table, const float* __restrict__ val_w,
    const float* __restrict__ val_b, const float* __restrict__ key_w,
    float* __restrict__ vbase, float* __restrict__ kraw)
{
  __shared__ int   hid[64][4];
  __shared__ float Ask[32][68];
  __shared__ float Ws[32][64];
  const int tid = threadIdx.x;
  const int i0  = blockIdx.x * 64;
  const int ct  = blockIdx.y;
  {
    const int r = tid >> 2, wh = tid & 3;
    const int i = i0 + r;
    const int b = i >> 7, tt = i & 127;
    const int* __restrict__ row = ids + b * TSEQ;
    const int g2 = row[tt];
    const int g1 = (tt >= 1) ? row[tt - 1] : 0;
    const int g0 = (tt >= 2) ? row[tt - 2] : 0;
    int h;
    if (wh == 0)      h = ((g1 * mults[0]) ^ (g2 * mults[1])) & 4095;
    else if (wh == 1) h = (((g1 * mults[3]) ^ (g2 * mults[4])) & 4095) + 4096;
    else if (wh == 2) h = (((g0 * mults[6]) ^ (g1 * mults[7]) ^ (g2 * mults[8])) & 4095) + 8192;
    else              h = (((g0 * mults[9]) ^ (g1 * mults[10]) ^ (g2 * mults[11])) & 4095) + 12288;
    hid[r][wh] = h;
  }
  const float* wbase;
  if (ct < 2) wbase = val_w + ct * 64;
  else { const int s = (ct - 2) >> 1; wbase = key_w + (size_t)s * 256 * 128 + ((ct - 2) & 1) * 64; }
  const int cq = tid & 15, rq = tid >> 4;
  float4 acc[4];
  acc[0] = acc[1] = acc[2] = acc[3] = make_float4(0.f, 0.f, 0.f, 0.f);
  __syncthreads();
  for (int kc = 0; kc < 8; ++kc) {
#pragma unroll
    for (int p = 0; p < 2; ++p) {
      const int idx = p * 256 + tid;
      const int r = idx >> 3, kof = (idx & 7) << 2;
      const int seg = kc >> 1;
      const int off = ((kc & 1) << 5) + kof;
      const float4 v = *reinterpret_cast<const float4*>(table + (size_t)hid[r][seg] * 64 + off);
      Ask[kof + 0][r] = v.x; Ask[kof + 1][r] = v.y;
      Ask[kof + 2][r] = v.z; Ask[kof + 3][r] = v.w;
    }
#pragma unroll
    for (int p = 0; p < 2; ++p) {
      const int idx = p * 256 + tid;
      const int kk = idx >> 4, cf = (idx & 15) << 2;
      *reinterpret_cast<float4*>(&Ws[kk][cf]) =
          *reinterpret_cast<const float4*>(wbase + (size_t)(kc * 32 + kk) * 128 + cf);
    }
    __syncthreads();
#pragma unroll
    for (int kk = 0; kk < 32; ++kk) {
      const float4 av = *reinterpret_cast<const float4*>(&Ask[kk][rq << 2]);
      const float4 wv = *reinterpret_cast<const float4*>(&Ws[kk][cq << 2]);
      fma4(acc[0], av.x, wv); fma4(acc[1], av.y, wv);
      fma4(acc[2], av.z, wv); fma4(acc[3], av.w, wv);
    }
    __syncthreads();
  }
  if (ct < 2) {
    const int c = ct * 64 + (cq << 2);
    const float4 bv = *reinterpret_cast<const float4*>(val_b + c);
#pragma unroll
    for (int u = 0; u < 4; ++u) {
      const int row = i0 + (rq << 2) + u;
      float4 o = acc[u];
      o.x += bv.x; o.y += bv.y; o.z += bv.z; o.w += bv.w;
      *reinterpret_cast<float4*>(vbase + (size_t)row * 128 + c) = o;
    }
  } else {
    const int c = (ct - 2) * 64 + (cq << 2);
#pragma unroll
    for (int u = 0; u < 4; ++u) {
      const int row = i0 + (rq << 2) + u;
      *reinterpret_cast<float4*>(kraw + (size_t)row * 512 + c) = acc[u];
    }
  }
}

// ---------------------------------------------------------------------------
// engram gates: per token (1 wave): rmsnorm(k_raw+key_b)*nk vs rmsnorm(x)*nq
// -> gate = sigmoid(dot/sqrt(128)); A = gate*rsqrt(gate^2*mean(vb^2)+eps)
// ---------------------------------------------------------------------------
__global__ __launch_bounds__(256) void eng_gate(
    const float* __restrict__ kraw, const float* __restrict__ x,
    const float* __restrict__ vbase, const float* __restrict__ key_b,
    const float* __restrict__ nk_w, const float* __restrict__ nq_w,
    float* __restrict__ gates, float* __restrict__ afac)
{
  const int tid = threadIdx.x;
  const int l = tid & 63;
  const size_t i = (size_t)blockIdx.x * 4 + (tid >> 6);
  const int s = l >> 4, li = l & 15;
  const int j0 = l * 8;
  const int c0 = li * 8;
  float kv[8], xv[8];
  {
    const float4 a = *reinterpret_cast<const float4*>(kraw + i * 512 + j0);
    const float4 b = *reinterpret_cast<const float4*>(kraw + i * 512 + j0 + 4);
    kv[0]=a.x; kv[1]=a.y; kv[2]=a.z; kv[3]=a.w; kv[4]=b.x; kv[5]=b.y; kv[6]=b.z; kv[7]=b.w;
  }
  {
    const float4 a = *reinterpret_cast<const float4*>(x + i * 512 + j0);
    const float4 b = *reinterpret_cast<const float4*>(x + i * 512 + j0 + 4);
    xv[0]=a.x; xv[1]=a.y; xv[2]=a.z; xv[3]=a.w; xv[4]=b.x; xv[5]=b.y; xv[6]=b.z; xv[7]=b.w;
  }
  float kb[8], nk[8], nq[8];
  {
    const float4 a = *reinterpret_cast<const float4*>(key_b + s * 128 + c0);
    const float4 b = *reinterpret_cast<const float4*>(key_b + s * 128 + c0 + 4);
    kb[0]=a.x; kb[1]=a.y; kb[2]=a.z; kb[3]=a.w; kb[4]=b.x; kb[5]=b.y; kb[6]=b.z; kb[7]=b.w;
  }
  {
    const float4 a = *reinterpret_cast<const float4*>(nk_w + s * 128 + c0);
    const float4 b = *reinterpret_cast<const float4*>(nk_w + s * 128 + c0 + 4);
    nk[0]=a.x; nk[1]=a.y; nk[2]=a.z; nk[3]=a.w; nk[4]=b.x; nk[5]=b.y; nk[6]=b.z; nk[7]=b.w;
  }
  {
    const float4 a = *reinterpret_cast<const float4*>(nq_w + s * 128 + c0);
    const float4 b = *reinterpret_cast<const float4*>(nq_w + s * 128 + c0 + 4);
    nq[0]=a.x; nq[1]=a.y; nq[2]=a.z; nq[3]=a.w; nq[4]=b.x; nq[5]=b.y; nq[6]=b.z; nq[7]=b.w;
  }
  float ssk = 0.f, ssx = 0.f;
#pragma unroll
  for (int jj = 0; jj < 8; ++jj) {
    kv[jj] += kb[jj];
    ssk = fmaf(kv[jj], kv[jj], ssk);
    ssx = fmaf(xv[jj], xv[jj], ssx);
  }
  ssk = red16(ssk);
  ssx = red16(ssx);
  const float invk = rsqrtf(ssk * (1.f / 128.f) + EPSF);
  const float invq = rsqrtf(ssx * (1.f / 128.f) + EPSF);
  float dot = 0.f;
#pragma unroll
  for (int jj = 0; jj < 8; ++jj)
    dot = fmaf(kv[jj] * invk * nk[jj], xv[jj] * invq * nq[jj], dot);
  dot = red16(dot);
  const float gate = sigm(dot * 0.08838834764831843f); // 1/sqrt(128)
  const float2 vb2 = *reinterpret_cast<const float2*>(vbase + i * 128 + l * 2);
  float ssv = vb2.x * vb2.x + vb2.y * vb2.y;
  ssv = red64(ssv);
  const float A = gate * rsqrtf(gate * gate * (ssv * (1.f / 128.f)) + EPSF);
  if (li == 0) { gates[i * 4 + s] = gate; afac[i * 4 + s] = A; }
}

// ---------------------------------------------------------------------------
// engram conv + residual: out = x + vb*gate + silu(cnw * sum_k vb[t-3+k]*A[t-3+k]*cw[k])
// ---------------------------------------------------------------------------
__global__ __launch_bounds__(256) void eng_conv(
    const float* __restrict__ x, const float* __restrict__ vbase,
    const float* __restrict__ gates, const float* __restrict__ afac,
    const float* __restrict__ conv_w, const float* __restrict__ cnw,
    float* __restrict__ xout)
{
  const size_t i = blockIdx.x;
  const int tt = (int)(i & 127);
  const int tid = threadIdx.x;
  __shared__ float sA[4][4]; // [k][s]
  __shared__ float sG[4];
  if (tid < 16) {
    const int kk = tid >> 2, s = tid & 3;
    const int t2 = tt - 3 + kk;
    sA[kk][s] = (t2 >= 0) ? afac[(i - 3 + kk) * 4 + s] : 0.f;
  } else if (tid < 20) {
    sG[tid - 16] = gates[i * 4 + (tid - 16)];
  }
  __syncthreads();
#pragma unroll
  for (int p = 0; p < 2; ++p) {
    const int j = tid + p * 256;
    const int s = j >> 7, c = j & 127;
    const float4 cw = *reinterpret_cast<const float4*>(conv_w + (size_t)j * 4);
    float accv = 0.f;
#pragma unroll
    for (int kk = 0; kk < 4; ++kk) {
      const int t2 = tt - 3 + kk;
      const float vb = (t2 >= 0) ? vbase[(i - 3 + kk) * 128 + c] : 0.f;
      const float w = (kk == 0) ? cw.x : (kk == 1) ? cw.y : (kk == 2) ? cw.z : cw.w;
      accv = fmaf(vb * sA[kk][s], w, accv);
    }
    const float yv = accv * cnw[s * 128 + c];
    const float sil = yv * sigm(yv);
    xout[i * 512 + j] = x[i * 512 + j] + vbase[i * 128 + c] * sG[s] + sil;
  }
}

// ---------------------------------------------------------------------------
// mhc head: per token (1 wave): rmsnorm512 -> H_pre/H_post/sinkhorn(H_res)
// -> x_agg + rmsnorm128 -> xa ; stores hres(16), hps(1)
// ---------------------------------------------------------------------------
__global__ __launch_bounds__(256) void mhc_head(
    const float* __restrict__ xin, const float* __restrict__ coef_w,
    const float* __restrict__ pre_w, const float* __restrict__ pre_b,
    const float* __restrict__ post_w, const float* __restrict__ post_b,
    const float* __restrict__ res_w, const float* __restrict__ res_b,
    const float* __restrict__ p_apre, const float* __restrict__ p_apost,
    const float* __restrict__ p_ares, const float* __restrict__ ln_w,
    float* __restrict__ xa, float* __restrict__ hres, float* __restrict__ hps)
{
  const int tid = threadIdx.x;
  const int l = tid & 63;
  const size_t i = (size_t)blockIdx.x * 4 + (tid >> 6);
  const int j0 = l * 8;
  float xv[8];
  {
    const float4 a = *reinterpret_cast<const float4*>(xin + i * 512 + j0);
    const float4 b = *reinterpret_cast<const float4*>(xin + i * 512 + j0 + 4);
    xv[0]=a.x; xv[1]=a.y; xv[2]=a.z; xv[3]=a.w; xv[4]=b.x; xv[5]=b.y; xv[6]=b.z; xv[7]=b.w;
  }
  float ss = 0.f;
#pragma unroll
  for (int jj = 0; jj < 8; ++jj) ss = fmaf(xv[jj], xv[jj], ss);
  ss = red64(ss);
  const float inv = rsqrtf(ss * (1.f / 512.f) + EPSF);
  float xn[8];
  {
    const float4 a = *reinterpret_cast<const float4*>(coef_w + j0);
    const float4 b = *reinterpret_cast<const float4*>(coef_w + j0 + 4);
    xn[0]=xv[0]*inv*a.x; xn[1]=xv[1]*inv*a.y; xn[2]=xv[2]*inv*a.z; xn[3]=xv[3]*inv*a.w;
    xn[4]=xv[4]*inv*b.x; xn[5]=xv[5]*inv*b.y; xn[6]=xv[6]*inv*b.z; xn[7]=xv[7]*inv*b.w;
  }
  float aP[4] = {0,0,0,0}, aQ[4] = {0,0,0,0};
  float aR[16];
#pragma unroll
  for (int t = 0; t < 16; ++t) aR[t] = 0.f;
#pragma unroll
  for (int jj = 0; jj < 8; ++jj) {
    const int j = j0 + jj;
    const float xnj = xn[jj];
    const float4 pw = *reinterpret_cast<const float4*>(pre_w + (size_t)j * 4);
    const float4 qw = *reinterpret_cast<const float4*>(post_w + (size_t)j * 4);
    aP[0]=fmaf(xnj,pw.x,aP[0]); aP[1]=fmaf(xnj,pw.y,aP[1]);
    aP[2]=fmaf(xnj,pw.z,aP[2]); aP[3]=fmaf(xnj,pw.w,aP[3]);
    aQ[0]=fmaf(xnj,qw.x,aQ[0]); aQ[1]=fmaf(xnj,qw.y,aQ[1]);
    aQ[2]=fmaf(xnj,qw.z,aQ[2]); aQ[3]=fmaf(xnj,qw.w,aQ[3]);
    const float4* rw = reinterpret_cast<const float4*>(res_w + (size_t)j * 16);
    const float4 r0 = rw[0], r1 = rw[1], r2 = rw[2], r3 = rw[3];
    aR[0]=fmaf(xnj,r0.x,aR[0]);  aR[1]=fmaf(xnj,r0.y,aR[1]);
    aR[2]=fmaf(xnj,r0.z,aR[2]);  aR[3]=fmaf(xnj,r0.w,aR[3]);
    aR[4]=fmaf(xnj,r1.x,aR[4]);  aR[5]=fmaf(xnj,r1.y,aR[5]);
    aR[6]=fmaf(xnj,r1.z,aR[6]);  aR[7]=fmaf(xnj,r1.w,aR[7]);
    aR[8]=fmaf(xnj,r2.x,aR[8]);  aR[9]=fmaf(xnj,r2.y,aR[9]);
    aR[10]=fmaf(xnj,r2.z,aR[10]); aR[11]=fmaf(xnj,r2.w,aR[11]);
    aR[12]=fmaf(xnj,r3.x,aR[12]); aR[13]=fmaf(xnj,r3.y,aR[13]);
    aR[14]=fmaf(xnj,r3.z,aR[14]); aR[15]=fmaf(xnj,r3.w,aR[15]);
  }
#pragma unroll
  for (int t = 0; t < 4; ++t) { aP[t] = red64(aP[t]); aQ[t] = red64(aQ[t]); }
#pragma unroll
  for (int t = 0; t < 16; ++t) aR[t] = red64(aR[t]);
  const float apre = p_apre[0], apost = p_apost[0], ares = p_ares[0];
  float hpn[4];
  float hsum = 0.f;
#pragma unroll
  for (int t = 0; t < 4; ++t) {
    hpn[t] = sigm(apre * (aP[t] + pre_b[t]));
    hsum += 2.f * sigm(apost * (aQ[t] + post_b[t]));
  }
  // sinkhorn on 16 lanes (lane li holds element (li>>2, li&3)); replicated x4
  const int li = l & 15;
  float v = ares * (aR[0] + res_b[0]);
#pragma unroll
  for (int t = 1; t < 16; ++t) {
    const float cand = ares * (aR[t] + res_b[t]);
    v = (li == t) ? cand : v;
  }
  float rm = fmaxf(v, __shfl_xor(v, 1));
  rm = fmaxf(rm, __shfl_xor(rm, 2));
  float m = __expf(v - rm);
#pragma unroll
  for (int it = 0; it < 20; ++it) {
    float rs = m;
    rs += __shfl_xor(rs, 1); rs += __shfl_xor(rs, 2);
    m = m / (rs + 1e-6f);
    float cs = m;
    cs += __shfl_xor(cs, 4); cs += __shfl_xor(cs, 8);
    m = m / (cs + 1e-6f);
  }
  if (l < 16) hres[i * 16 + l] = m;
  if (l == 0) hps[i] = hsum;
  // x_agg = sum_n hpre[n] * x[n*128+c] ; then rmsnorm128 * ln_w
  const int n = l >> 4;
  float hp = hpn[0];
  hp = (n == 1) ? hpn[1] : hp;
  hp = (n == 2) ? hpn[2] : hp;
  hp = (n == 3) ? hpn[3] : hp;
  float ag[8];
#pragma unroll
  for (int jj = 0; jj < 8; ++jj) {
    float a2 = hp * xv[jj];
    a2 += __shfl_xor(a2, 16);
    a2 += __shfl_xor(a2, 32);
    ag[jj] = a2;
  }
  float ssa = 0.f;
#pragma unroll
  for (int jj = 0; jj < 8; ++jj) ssa = fmaf(ag[jj], ag[jj], ssa);
  ssa = red16(ssa);
  const float inva = rsqrtf(ssa * (1.f / 128.f) + EPSF);
  if (l < 16) {
    const int c0 = l * 8;
    const float4 wa = *reinterpret_cast<const float4*>(ln_w + c0);
    const float4 wb = *reinterpret_cast<const float4*>(ln_w + c0 + 4);
    const float4 o1 = make_float4(ag[0]*inva*wa.x, ag[1]*inva*wa.y, ag[2]*inva*wa.z, ag[3]*inva*wa.w);
    const float4 o2 = make_float4(ag[4]*inva*wb.x, ag[5]*inva*wb.y, ag[6]*inva*wb.z, ag[7]*inva*wb.w);
    *reinterpret_cast<float4*>(xa + i * 128 + c0) = o1;
    *reinterpret_cast<float4*>(xa + i * 128 + c0 + 4) = o2;
  }
}

// ---------------------------------------------------------------------------
// generic f32 GEMM: out[M x N] = act(A[M x K] @ W[K x N] + bias)
// 64x64 tile, 4x4 micro-tile, A staged k-major in LDS. ACT: 0=none, 1=silu
// ---------------------------------------------------------------------------
template <int ACT>
__global__ __launch_bounds__(256) void gemm_rw(
    const float* __restrict__ A, const int lda,
    const float* __restrict__ W, const int ldw,
    const float* __restrict__ bias,
    float* __restrict__ out, const int ldo, const int K)
{
  __shared__ float Ask[32][68];
  __shared__ float Ws[32][64];
  const int tid = threadIdx.x;
  const int i0 = blockIdx.x * 64;
  const int c0 = blockIdx.y * 64;
  const int cq = tid & 15, rq = tid >> 4;
  float4 acc[4];
  acc[0] = acc[1] = acc[2] = acc[3] = make_float4(0.f, 0.f, 0.f, 0.f);
  for (int kc = 0; kc < K; kc += 32) {
#pragma unroll
    for (int p = 0; p < 2; ++p) {
      const int idx = p * 256 + tid;
      const int r = idx >> 3, kof = (idx & 7) << 2;
      const float4 v = *reinterpret_cast<const float4*>(A + (size_t)(i0 + r) * lda + kc + kof);
      Ask[kof + 0][r] = v.x; Ask[kof + 1][r] = v.y;
      Ask[kof + 2][r] = v.z; Ask[kof + 3][r] = v.w;
    }
#pragma unroll
    for (int p = 0; p < 2; ++p) {
      const int idx = p * 256 + tid;
      const int kk = idx >> 4, cf = (idx & 15) << 2;
      *reinterpret_cast<float4*>(&Ws[kk][cf]) =
          *reinterpret_cast<const float4*>(W + (size_t)(kc + kk) * ldw + c0 + cf);
    }
    __syncthreads();
#pragma unroll
    for (int kk = 0; kk < 32; ++kk) {
      const float4 av = *reinterpret_cast<const float4*>(&Ask[kk][rq << 2]);
      const float4 wv = *reinterpret_cast<const float4*>(&Ws[kk][cq << 2]);
      fma4(acc[0], av.x, wv); fma4(acc[1], av.y, wv);
      fma4(acc[2], av.z, wv); fma4(acc[3], av.w, wv);
    }
    __syncthreads();
  }
  const float4 bv = *reinterpret_cast<const float4*>(bias + c0 + (cq << 2));
#pragma unroll
  for (int u = 0; u < 4; ++u) {
    float4 o = acc[u];
    o.x += bv.x; o.y += bv.y; o.z += bv.z; o.w += bv.w;
    if (ACT == 1) {
      o.x = o.x * sigm(o.x); o.y = o.y * sigm(o.y);
      o.z = o.z * sigm(o.z); o.w = o.w * sigm(o.w);
    }
    *reinterpret_cast<float4*>(out + (size_t)(i0 + (rq << 2) + u) * ldo + c0 + (cq << 2)) = o;
  }
}

// ---------------------------------------------------------------------------
// causal attention per (b,h): T=128, D=32. qkv rows are [q|k|v] 384-wide.
// thread: row = tid>>2 (+64 second pass), s-quarter = (tid&3)*32.
// Writes y (pre-proj), layout [BT][128] col h*32+d.
// ---------------------------------------------------------------------------
__global__ __launch_bounds__(256) void attn_kern(
    const float* __restrict__ qkv, float* __restrict__ y)
{
  __shared__ float Qs[128][36];
  __shared__ float Ks[128][36];
  __shared__ float Vs[128][36];
  const int tid = threadIdx.x;
  const int b = blockIdx.x >> 2, h = blockIdx.x & 3;
  const float* __restrict__ src0 = qkv + (size_t)b * 128 * 384 + h * 32;
#pragma unroll
  for (int p = 0; p < 4; ++p) {
    const int idx = p * 256 + tid;
    const int row = idx >> 3, f4 = (idx & 7) << 2;
    const float* s = src0 + (size_t)row * 384 + f4;
    *reinterpret_cast<float4*>(&Qs[row][f4]) = *reinterpret_cast<const float4*>(s);
    *reinterpret_cast<float4*>(&Ks[row][f4]) = *reinterpret_cast<const float4*>(s + 128);
    *reinterpret_cast<float4*>(&Vs[row][f4]) = *reinterpret_cast<const float4*>(s + 256);
  }
  __syncthreads();
  const int rbase = tid >> 2;
  const int s0 = (tid & 3) << 5;
  const float scl = 0.17677669529663687f; // 1/sqrt(32)
  for (int half = 0; half < 2; ++half) {
    const int row = rbase + half * 64;
    float4 q4[8];
#pragma unroll
    for (int dd = 0; dd < 8; ++dd) q4[dd] = *reinterpret_cast<const float4*>(&Qs[row][dd << 2]);
    float sc[32];
    float mx = -3.4e38f;
#pragma unroll
    for (int is = 0; is < 32; ++is) {
      const int s = s0 + is;
      float acc = 0.f;
#pragma unroll
      for (int dd = 0; dd < 8; ++dd)
        acc = dot4(q4[dd], *reinterpret_cast<const float4*>(&Ks[s][dd << 2]), acc);
      if (s <= row) { sc[is] = acc * scl; mx = fmaxf(mx, sc[is]); }
      else sc[is] = 0.f;
    }
    mx = fmaxf(mx, __shfl_xor(mx, 1));
    mx = fmaxf(mx, __shfl_xor(mx, 2));
    float sum = 0.f;
#pragma unroll
    for (int is = 0; is < 32; ++is) {
      const float p = (s0 + is <= row) ? __expf(sc[is] - mx) : 0.f;
      sc[is] = p;
      sum += p;
    }
    sum += __shfl_xor(sum, 1);
    sum += __shfl_xor(sum, 2);
    const float rinv = 1.f / sum;
    float4 ac[8];
#pragma unroll
    for (int dd = 0; dd < 8; ++dd) ac[dd] = make_float4(0.f, 0.f, 0.f, 0.f);
#pragma unroll
    for (int is = 0; is < 32; ++is) {
      const float p = sc[is];
      const int s = s0 + is;
#pragma unroll
      for (int dd = 0; dd < 8; ++dd)
        fma4(ac[dd], p, *reinterpret_cast<const float4*>(&Vs[s][dd << 2]));
    }
#pragma unroll
    for (int dd = 0; dd < 8; ++dd) {
      ac[dd].x += __shfl_xor(ac[dd].x, 1); ac[dd].x += __shfl_xor(ac[dd].x, 2);
      ac[dd].y += __shfl_xor(ac[dd].y, 1); ac[dd].y += __shfl_xor(ac[dd].y, 2);
      ac[dd].z += __shfl_xor(ac[dd].z, 1); ac[dd].z += __shfl_xor(ac[dd].z, 2);
      ac[dd].w += __shfl_xor(ac[dd].w, 1); ac[dd].w += __shfl_xor(ac[dd].w, 2);
    }
    if ((tid & 3) == 0) {
      float* dst = y + ((size_t)b * 128 + row) * 128 + h * 32;
#pragma unroll
      for (int dd = 0; dd < 8; ++dd) {
        const float4 o = make_float4(ac[dd].x * rinv, ac[dd].y * rinv,
                                     ac[dd].z * rinv, ac[dd].w * rinv);
        *reinterpret_cast<float4*>(dst + (dd << 2)) = o;
      }
    }
  }
}

// ---------------------------------------------------------------------------
// mhc combine: out[n*128+c] = sum_m H[n,m]*xst[m*128+c] + hps * yv[c]
// ---------------------------------------------------------------------------
__global__ __launch_bounds__(128) void mhc_combine(
    const float* __restrict__ xst, const float* __restrict__ hres,
    const float* __restrict__ hps, const float* __restrict__ yv,
    float* __restrict__ out)
{
  const size_t i = blockIdx.x;
  const int c = threadIdx.x;
  __shared__ float H[16];
  __shared__ float g;
  if (c < 16) H[c] = hres[i * 16 + c];
  if (c == 16) g = hps[i];
  __syncthreads();
  const float x0 = xst[i * 512 + c];
  const float x1 = xst[i * 512 + 128 + c];
  const float x2 = xst[i * 512 + 256 + c];
  const float x3 = xst[i * 512 + 384 + c];
  const float yb = g * yv[i * 128 + c];
  out[i * 512 +       c] = H[0]  * x0 + H[1]  * x1 + H[2]  * x2 + H[3]  * x3 + yb;
  out[i * 512 + 128 + c] = H[4]  * x0 + H[5]  * x1 + H[6]  * x2 + H[7]  * x3 + yb;
  out[i * 512 + 256 + c] = H[8]  * x0 + H[9]  * x1 + H[10] * x2 + H[11] * x3 + yb;
  out[i * 512 + 384 + c] = H[12] * x0 + H[13] * x1 + H[14] * x2 + H[15] * x3 + yb;
}

// ---------------------------------------------------------------------------
extern "C" void kernel_launch(void* const* d_in, const int* in_sizes, int n_in,
                              void* d_out, int out_size, void* d_ws, size_t ws_size,
                              hipStream_t stream)
{
  const float* x        = (const float*)d_in[0];
  const int*   ids      = (const int*)d_in[1];
  const int*   mults    = (const int*)d_in[2];
  const float* table    = (const float*)d_in[3];
  const float* val_w    = (const float*)d_in[4];
  const float* val_b    = (const float*)d_in[5];
  const float* key_w    = (const float*)d_in[6];
  const float* key_b    = (const float*)d_in[7];
  const float* nq_w     = (const float*)d_in[8];
  const float* nk_w     = (const float*)d_in[9];
  const float* conv_w   = (const float*)d_in[10];
  const float* cnw      = (const float*)d_in[11];
  const float* a_coef   = (const float*)d_in[12];
  const float* a_pre_w  = (const float*)d_in[13];
  const float* a_pre_b  = (const float*)d_in[14];
  const float* a_post_w = (const float*)d_in[15];
  const float* a_post_b = (const float*)d_in[16];
  const float* a_res_w  = (const float*)d_in[17];
  const float* a_res_b  = (const float*)d_in[18];
  const float* a_apre   = (const float*)d_in[19];
  const float* a_apost  = (const float*)d_in[20];
  const float* a_ares   = (const float*)d_in[21];
  const float* a_ln_w   = (const float*)d_in[22];
  const float* qkv_w    = (const float*)d_in[23];
  const float* qkv_b    = (const float*)d_in[24];
  const float* proj_w   = (const float*)d_in[25];
  const float* proj_b   = (const float*)d_in[26];
  const float* m_coef   = (const float*)d_in[27];
  const float* m_pre_w  = (const float*)d_in[28];
  const float* m_pre_b  = (const float*)d_in[29];
  const float* m_post_w = (const float*)d_in[30];
  const float* m_post_b = (const float*)d_in[31];
  const float* m_res_w  = (const float*)d_in[32];
  const float* m_res_b  = (const float*)d_in[33];
  const float* m_apre   = (const float*)d_in[34];
  const float* m_apost  = (const float*)d_in[35];
  const float* m_ares   = (const float*)d_in[36];
  const float* m_ln_w   = (const float*)d_in[37];
  const float* mlp_w1   = (const float*)d_in[38];
  const float* mlp_b1   = (const float*)d_in[39];
  const float* mlp_w2   = (const float*)d_in[40];
  const float* mlp_b2   = (const float*)d_in[41];

  float* out = (float*)d_out;
  float* ws  = (float*)d_ws;
  // workspace layout (f32): total 34,373,632 floats = 137.5 MB
  float* vbase = ws;                       // BT*128  v_base
  float* kraw  = vbase + (size_t)BT * 128; // BT*512  k_raw -> qkv -> x2
  float* gates = kraw  + (size_t)BT * 512; // BT*4
  float* afac  = gates + (size_t)BT * 4;   // BT*4
  float* xa    = afac  + (size_t)BT * 4;   // BT*128  normed aggregate
  float* y1    = xa    + (size_t)BT * 128; // BT*128  attn out (pre-proj)
  float* y2    = y1    + (size_t)BT * 128; // BT*128  proj / mlp out
  float* hresb = y2    + (size_t)BT * 128; // BT*16
  float* hpsb  = hresb + (size_t)BT * 16;  // BT

  // ---- engram ----
  eng_gemm<<<dim3(BT / 64, 10), 256, 0, stream>>>(ids, mults, table, val_w, val_b, key_w,
                                                  vbase, kraw);
  eng_gate<<<BT / 4, 256, 0, stream>>>(kraw, x, vbase, key_b, nk_w, nq_w, gates, afac);
  eng_conv<<<BT, 256, 0, stream>>>(x, vbase, gates, afac, conv_w, cnw, out); // x1 -> d_out

  // ---- mhc (attention) ----
  mhc_head<<<BT / 4, 256, 0, stream>>>(out, a_coef, a_pre_w, a_pre_b, a_post_w, a_post_b,
                                       a_res_w, a_res_b, a_apre, a_apost, a_ares, a_ln_w,
                                       xa, hresb, hpsb);
  gemm_rw<0><<<dim3(BT / 64, 6), 256, 0, stream>>>(xa, 128, qkv_w, 384, qkv_b, kraw, 384, 128);
  attn_kern<<<1024, 256, 0, stream>>>(kraw, y1);
  gemm_rw<0><<<dim3(BT / 64, 2), 256, 0, stream>>>(y1, 128, proj_w, 128, proj_b, y2, 128, 128);
  mhc_combine<<<BT, 128, 0, stream>>>(out, hresb, hpsb, y2, kraw); // x2 -> kraw

  // ---- mhc (mlp) ----
  mhc_head<<<BT / 4, 256, 0, stream>>>(kraw, m_coef, m_pre_w, m_pre_b, m_post_w, m_post_b,
                                       m_res_w, m_res_b, m_apre, m_apost, m_ares, m_ln_w,
                                       xa, hresb, hpsb);
  gemm_rw<1><<<dim3(BT / 64, 8), 256, 0, stream>>>(xa, 128, mlp_w1, 512, mlp_b1, out, 512, 128);
  gemm_rw<0><<<dim3(BT / 64, 2), 256, 0, stream>>>(out, 512, mlp_w2, 128, mlp_b2, y2, 128, 512);
  mhc_combine<<<BT, 128, 0, stream>>>(kraw, hresb, hpsb, y2, out);

  (void)in_sizes; (void)n_in; (void)out_size; (void)ws_size;
}

// Round 2
// 468.892 us; speedup vs baseline: 1.8874x; 1.8874x over previous
//
#include <hip/hip_runtime.h>

#define BT 32768
#define TSEQ 128

constexpr float EPSF = 1.1920929e-07f;

typedef __attribute__((ext_vector_type(8))) short bf16x8;
typedef __attribute__((ext_vector_type(4))) float f32x4;

__device__ __forceinline__ float sigm(float z) { return 1.f / (1.f + __expf(-z)); }

__device__ __forceinline__ short bf16c(float f) {
  union { float f; unsigned u; } v; v.f = f;
  unsigned r = v.u + 0x7FFFu + ((v.u >> 16) & 1u);
  return (short)(r >> 16);
}

__device__ __forceinline__ float red64(float v) {
  v += __shfl_xor(v, 1);  v += __shfl_xor(v, 2);  v += __shfl_xor(v, 4);
  v += __shfl_xor(v, 8);  v += __shfl_xor(v, 16); v += __shfl_xor(v, 32);
  return v;
}
__device__ __forceinline__ float red16(float v) {
  v += __shfl_xor(v, 1); v += __shfl_xor(v, 2); v += __shfl_xor(v, 4); v += __shfl_xor(v, 8);
  return v;
}
__device__ __forceinline__ void fma4(float4& a, float s, const float4& b) {
  a.x = fmaf(s, b.x, a.x); a.y = fmaf(s, b.y, a.y);
  a.z = fmaf(s, b.z, a.z); a.w = fmaf(s, b.w, a.w);
}
__device__ __forceinline__ float dot4(const float4& a, const float4& b, float acc) {
  acc = fmaf(a.x, b.x, acc); acc = fmaf(a.y, b.y, acc);
  acc = fmaf(a.z, b.z, acc); acc = fmaf(a.w, b.w, acc);
  return acc;
}

// ---------------------------------------------------------------------------
// prep: build bf16 transposed weights [N][K] + packed mhc weights/biases.
// ---------------------------------------------------------------------------
__global__ __launch_bounds__(256) void prep(
    const float* __restrict__ qkv_w, const float* __restrict__ proj_w,
    const float* __restrict__ mlp_w1, const float* __restrict__ mlp_w2,
    const float* __restrict__ val_w, const float* __restrict__ key_w,
    const float* __restrict__ a_res_w, const float* __restrict__ a_pre_w,
    const float* __restrict__ a_post_w,
    const float* __restrict__ m_res_w, const float* __restrict__ m_pre_w,
    const float* __restrict__ m_post_w,
    const float* __restrict__ a_res_b, const float* __restrict__ a_pre_b,
    const float* __restrict__ a_post_b,
    const float* __restrict__ m_res_b, const float* __restrict__ m_pre_b,
    const float* __restrict__ m_post_b,
    short* __restrict__ wt_qkv, short* __restrict__ wt_proj,
    short* __restrict__ wt_mlp1, short* __restrict__ wt_mlp2,
    short* __restrict__ wt_eng, short* __restrict__ wpk_a,
    short* __restrict__ wpk_m, float* __restrict__ bpk_a,
    float* __restrict__ bpk_m)
{
  const int idx = blockIdx.x * 256 + threadIdx.x;
  if (idx < 49152) {
    const int n = idx >> 7, k = idx & 127;
    wt_qkv[idx] = bf16c(qkv_w[k * 384 + n]);
  } else if (idx < 65536) {
    const int j = idx - 49152; const int n = j >> 7, k = j & 127;
    wt_proj[j] = bf16c(proj_w[k * 128 + n]);
  } else if (idx < 131072) {
    const int j = idx - 65536; const int n = j >> 7, k = j & 127;
    wt_mlp1[j] = bf16c(mlp_w1[k * 512 + n]);
  } else if (idx < 196608) {
    const int j = idx - 131072; const int n = j >> 9, k = j & 511;
    wt_mlp2[j] = bf16c(mlp_w2[k * 128 + n]);
  } else if (idx < 360448) {
    const int j = idx - 196608; const int n = j >> 8, k = j & 255;
    float v;
    if (n < 128) v = val_w[k * 128 + n];
    else v = key_w[(size_t)((n - 128) >> 7) * 32768 + k * 128 + (n & 127)];
    wt_eng[j] = bf16c(v);
  } else if (idx < 376832) {
    const int j = idx - 360448; const int r = j >> 9, k = j & 511;
    float v = 0.f;
    if (r < 16) v = a_res_w[k * 16 + r];
    else if (r < 20) v = a_pre_w[k * 4 + (r - 16)];
    else if (r < 24) v = a_post_w[k * 4 + (r - 20)];
    wpk_a[j] = bf16c(v);
  } else if (idx < 393216) {
    const int j = idx - 376832; const int r = j >> 9, k = j & 511;
    float v = 0.f;
    if (r < 16) v = m_res_w[k * 16 + r];
    else if (r < 20) v = m_pre_w[k * 4 + (r - 16)];
    else if (r < 24) v = m_post_w[k * 4 + (r - 20)];
    wpk_m[j] = bf16c(v);
  } else if (idx < 393280) {
    const int j = idx - 393216;
    if (j < 32) {
      float v = 0.f;
      if (j < 16) v = a_res_b[j];
      else if (j < 20) v = a_pre_b[j - 16];
      else if (j < 24) v = a_post_b[j - 20];
      bpk_a[j] = v;
    } else {
      const int r = j - 32;
      float v = 0.f;
      if (r < 16) v = m_res_b[r];
      else if (r < 20) v = m_pre_b[r - 16];
      else if (r < 24) v = m_post_b[r - 20];
      bpk_m[r] = v;
    }
  }
}

// ---------------------------------------------------------------------------
// MFMA GEMM: out[M x N](f32) = act(A[M x K](f32) @ WT^T + bias)
// WT is bf16 [N][K] row-major. Tile 128x128, BK=64, 4 waves (2x2 of 64x64).
// SCALED: A[r][k] *= rinv[r]*csc[k] during staging (fused rmsnorm).
// ---------------------------------------------------------------------------
template <int ACT, bool SCALED>
__global__ __launch_bounds__(256) void mgemm(
    const float* __restrict__ A, const int lda,
    const short* __restrict__ WT, const float* __restrict__ bias,
    float* __restrict__ out, const int ldo, const int K,
    const float* __restrict__ rinv, const float* __restrict__ csc)
{
  __shared__ short As[128 * 64];
  __shared__ short Bs[128 * 64];
  const int tid = threadIdx.x;
  const int i0 = blockIdx.x * 128;
  const int c0 = blockIdx.y * 128;
  const int w = tid >> 6, l = tid & 63;
  const int wr = (w >> 1) * 64, wc = (w & 1) * 64;
  f32x4 acc[4][4];
#pragma unroll
  for (int mi = 0; mi < 4; ++mi)
#pragma unroll
    for (int ni = 0; ni < 4; ++ni) acc[mi][ni] = {0.f, 0.f, 0.f, 0.f};

  const int c4 = tid & 15;
  const int asl = c4 >> 1, ahf = c4 & 1;
  const int bsl = tid & 7;

  for (int kc = 0; kc < K; kc += 64) {
    __syncthreads();
#pragma unroll
    for (int p = 0; p < 8; ++p) {
      const int r = (tid >> 4) + p * 16;
      float4 v = *reinterpret_cast<const float4*>(A + (size_t)(i0 + r) * lda + kc + c4 * 4);
      if (SCALED) {
        const float rs = rinv[i0 + r];
        const float4 cs = *reinterpret_cast<const float4*>(csc + kc + c4 * 4);
        v.x *= rs * cs.x; v.y *= rs * cs.y; v.z *= rs * cs.z; v.w *= rs * cs.w;
      }
      short4 b4; b4.x = bf16c(v.x); b4.y = bf16c(v.y); b4.z = bf16c(v.z); b4.w = bf16c(v.w);
      *reinterpret_cast<short4*>(&As[r * 64 + ((asl ^ (r & 7)) << 3) + (ahf << 2)]) = b4;
    }
#pragma unroll
    for (int p = 0; p < 4; ++p) {
      const int r = (tid >> 3) + p * 32;
      const bf16x8 v = *reinterpret_cast<const bf16x8*>(WT + (size_t)(c0 + r) * K + kc + bsl * 8);
      *reinterpret_cast<bf16x8*>(&Bs[r * 64 + ((bsl ^ (r & 7)) << 3)]) = v;
    }
    __syncthreads();
    const int kg = l >> 4, lr = l & 15;
#pragma unroll
    for (int ks = 0; ks < 2; ++ks) {
      const int slot = ks * 4 + kg;
      bf16x8 af[4], bft[4];
#pragma unroll
      for (int mi = 0; mi < 4; ++mi) {
        const int r = wr + mi * 16 + lr;
        af[mi] = *reinterpret_cast<const bf16x8*>(&As[r * 64 + ((slot ^ (r & 7)) << 3)]);
      }
#pragma unroll
      for (int ni = 0; ni < 4; ++ni) {
        const int r = wc + ni * 16 + lr;
        bft[ni] = *reinterpret_cast<const bf16x8*>(&Bs[r * 64 + ((slot ^ (r & 7)) << 3)]);
      }
#pragma unroll
      for (int mi = 0; mi < 4; ++mi)
#pragma unroll
        for (int ni = 0; ni < 4; ++ni)
          acc[mi][ni] = __builtin_amdgcn_mfma_f32_16x16x32_bf16(af[mi], bft[ni], acc[mi][ni], 0, 0, 0);
    }
  }
  const int lr = l & 15, hi = l >> 4;
#pragma unroll
  for (int mi = 0; mi < 4; ++mi)
#pragma unroll
    for (int ni = 0; ni < 4; ++ni) {
      const int col = c0 + wc + ni * 16 + lr;
      const float bv = bias[col];
#pragma unroll
      for (int j = 0; j < 4; ++j) {
        const int row = i0 + wr + mi * 16 + hi * 4 + j;
        float o = acc[mi][ni][j] + bv;
        if (ACT == 1) o = o * sigm(o);
        out[(size_t)row * ldo + col] = o;
      }
    }
}

// ---------------------------------------------------------------------------
// MFMA GEMM, N=32 (mhc projection). Tile 128x32, BK=64, 4 waves (32 rows ea).
// Always SCALED (fused rmsnorm: A*rinv[row]*csc[k]).
// ---------------------------------------------------------------------------
__global__ __launch_bounds__(256) void mgemm32(
    const float* __restrict__ A, const int lda,
    const short* __restrict__ WT, const float* __restrict__ bias,
    float* __restrict__ out, const int K,
    const float* __restrict__ rinv, const float* __restrict__ csc)
{
  __shared__ short As[128 * 64];
  __shared__ short Bs[32 * 64];
  const int tid = threadIdx.x;
  const int i0 = blockIdx.x * 128;
  const int w = tid >> 6, l = tid & 63;
  const int wr = w * 32;
  f32x4 acc[2][2];
#pragma unroll
  for (int mi = 0; mi < 2; ++mi)
#pragma unroll
    for (int ni = 0; ni < 2; ++ni) acc[mi][ni] = {0.f, 0.f, 0.f, 0.f};

  const int c4 = tid & 15;
  const int asl = c4 >> 1, ahf = c4 & 1;

  for (int kc = 0; kc < K; kc += 64) {
    __syncthreads();
#pragma unroll
    for (int p = 0; p < 8; ++p) {
      const int r = (tid >> 4) + p * 16;
      float4 v = *reinterpret_cast<const float4*>(A + (size_t)(i0 + r) * lda + kc + c4 * 4);
      const float rs = rinv[i0 + r];
      const float4 cs = *reinterpret_cast<const float4*>(csc + kc + c4 * 4);
      v.x *= rs * cs.x; v.y *= rs * cs.y; v.z *= rs * cs.z; v.w *= rs * cs.w;
      short4 b4; b4.x = bf16c(v.x); b4.y = bf16c(v.y); b4.z = bf16c(v.z); b4.w = bf16c(v.w);
      *reinterpret_cast<short4*>(&As[r * 64 + ((asl ^ (r & 7)) << 3) + (ahf << 2)]) = b4;
    }
    {
      const int r = tid >> 3, slb = tid & 7;
      const bf16x8 v = *reinterpret_cast<const bf16x8*>(WT + (size_t)r * K + kc + slb * 8);
      *reinterpret_cast<bf16x8*>(&Bs[r * 64 + ((slb ^ (r & 7)) << 3)]) = v;
    }
    __syncthreads();
    const int kg = l >> 4, lr = l & 15;
#pragma unroll
    for (int ks = 0; ks < 2; ++ks) {
      const int slot = ks * 4 + kg;
      bf16x8 af[2], bft[2];
#pragma unroll
      for (int mi = 0; mi < 2; ++mi) {
        const int r = wr + mi * 16 + lr;
        af[mi] = *reinterpret_cast<const bf16x8*>(&As[r * 64 + ((slot ^ (r & 7)) << 3)]);
      }
#pragma unroll
      for (int ni = 0; ni < 2; ++ni) {
        const int r = ni * 16 + lr;
        bft[ni] = *reinterpret_cast<const bf16x8*>(&Bs[r * 64 + ((slot ^ (r & 7)) << 3)]);
      }
#pragma unroll
      for (int mi = 0; mi < 2; ++mi)
#pragma unroll
        for (int ni = 0; ni < 2; ++ni)
          acc[mi][ni] = __builtin_amdgcn_mfma_f32_16x16x32_bf16(af[mi], bft[ni], acc[mi][ni], 0, 0, 0);
    }
  }
  const int lr = l & 15, hi = l >> 4;
#pragma unroll
  for (int mi = 0; mi < 2; ++mi)
#pragma unroll
    for (int ni = 0; ni < 2; ++ni) {
      const int col = ni * 16 + lr;
      const float bv = bias[col];
#pragma unroll
      for (int j = 0; j < 4; ++j) {
        const int row = i0 + wr + mi * 16 + hi * 4 + j;
        out[(size_t)row * 32 + col] = acc[mi][ni][j] + bv;
      }
    }
}

// ---------------------------------------------------------------------------
// engram MFMA GEMM: ngram-hash + embedding gather fused into A staging.
// K=256 (4 gathered 64-wide segments). blockIdx.y: 0 -> vbase, 1..4 -> kraw.
// ---------------------------------------------------------------------------
__global__ __launch_bounds__(256) void eng_mgemm(
    const int* __restrict__ ids, const int* __restrict__ mults,
    const float* __restrict__ table, const float* __restrict__ val_b,
    const short* __restrict__ wt_eng,
    float* __restrict__ vbase, float* __restrict__ kraw)
{
  __shared__ int hid[128][4];
  __shared__ short As[128 * 64];
  __shared__ short Bs[128 * 64];
  const int tid = threadIdx.x;
  const int i0 = blockIdx.x * 128;
  const int by = blockIdx.y;
  const int c0 = by * 128;
#pragma unroll
  for (int p = 0; p < 2; ++p) {
    const int idx = tid + p * 256;
    const int r = idx >> 2, wh = idx & 3;
    const int i = i0 + r;
    const int b = i >> 7, tt = i & 127;
    const int* __restrict__ row = ids + b * TSEQ;
    const int g2 = row[tt];
    const int g1 = (tt >= 1) ? row[tt - 1] : 0;
    const int g0 = (tt >= 2) ? row[tt - 2] : 0;
    int h;
    if (wh == 0)      h = ((g1 * mults[0]) ^ (g2 * mults[1])) & 4095;
    else if (wh == 1) h = (((g1 * mults[3]) ^ (g2 * mults[4])) & 4095) + 4096;
    else if (wh == 2) h = (((g0 * mults[6]) ^ (g1 * mults[7]) ^ (g2 * mults[8])) & 4095) + 8192;
    else              h = (((g0 * mults[9]) ^ (g1 * mults[10]) ^ (g2 * mults[11])) & 4095) + 12288;
    hid[r][wh] = h;
  }
  const int w = tid >> 6, l = tid & 63;
  const int wr = (w >> 1) * 64, wc = (w & 1) * 64;
  f32x4 acc[4][4];
#pragma unroll
  for (int mi = 0; mi < 4; ++mi)
#pragma unroll
    for (int ni = 0; ni < 4; ++ni) acc[mi][ni] = {0.f, 0.f, 0.f, 0.f};

  const int c4 = tid & 15;
  const int asl = c4 >> 1, ahf = c4 & 1;
  const int bsl = tid & 7;

  for (int kc = 0; kc < 256; kc += 64) {
    const int seg = kc >> 6;
    __syncthreads();
#pragma unroll
    for (int p = 0; p < 8; ++p) {
      const int r = (tid >> 4) + p * 16;
      const float4 v = *reinterpret_cast<const float4*>(table + (size_t)hid[r][seg] * 64 + c4 * 4);
      short4 b4; b4.x = bf16c(v.x); b4.y = bf16c(v.y); b4.z = bf16c(v.z); b4.w = bf16c(v.w);
      *reinterpret_cast<short4*>(&As[r * 64 + ((asl ^ (r & 7)) << 3) + (ahf << 2)]) = b4;
    }
#pragma unroll
    for (int p = 0; p < 4; ++p) {
      const int r = (tid >> 3) + p * 32;
      const bf16x8 v = *reinterpret_cast<const bf16x8*>(wt_eng + (size_t)(c0 + r) * 256 + kc + bsl * 8);
      *reinterpret_cast<bf16x8*>(&Bs[r * 64 + ((bsl ^ (r & 7)) << 3)]) = v;
    }
    __syncthreads();
    const int kg = l >> 4, lr = l & 15;
#pragma unroll
    for (int ks = 0; ks < 2; ++ks) {
      const int slot = ks * 4 + kg;
      bf16x8 af[4], bft[4];
#pragma unroll
      for (int mi = 0; mi < 4; ++mi) {
        const int r = wr + mi * 16 + lr;
        af[mi] = *reinterpret_cast<const bf16x8*>(&As[r * 64 + ((slot ^ (r & 7)) << 3)]);
      }
#pragma unroll
      for (int ni = 0; ni < 4; ++ni) {
        const int r = wc + ni * 16 + lr;
        bft[ni] = *reinterpret_cast<const bf16x8*>(&Bs[r * 64 + ((slot ^ (r & 7)) << 3)]);
      }
#pragma unroll
      for (int mi = 0; mi < 4; ++mi)
#pragma unroll
        for (int ni = 0; ni < 4; ++ni)
          acc[mi][ni] = __builtin_amdgcn_mfma_f32_16x16x32_bf16(af[mi], bft[ni], acc[mi][ni], 0, 0, 0);
    }
  }
  const int lr = l & 15, hi = l >> 4;
#pragma unroll
  for (int mi = 0; mi < 4; ++mi)
#pragma unroll
    for (int ni = 0; ni < 4; ++ni) {
      const int col = wc + ni * 16 + lr;
#pragma unroll
      for (int j = 0; j < 4; ++j) {
        const int row = i0 + wr + mi * 16 + hi * 4 + j;
        if (by == 0)
          vbase[(size_t)row * 128 + col] = acc[mi][ni][j] + val_b[col];
        else
          kraw[(size_t)row * 512 + (by - 1) * 128 + col] = acc[mi][ni][j];
      }
    }
}

// ---------------------------------------------------------------------------
// engram gates (unchanged from R1)
// ---------------------------------------------------------------------------
__global__ __launch_bounds__(256) void eng_gate(
    const float* __restrict__ kraw, const float* __restrict__ x,
    const float* __restrict__ vbase, const float* __restrict__ key_b,
    const float* __restrict__ nk_w, const float* __restrict__ nq_w,
    float* __restrict__ gates, float* __restrict__ afac)
{
  const int tid = threadIdx.x;
  const int l = tid & 63;
  const size_t i = (size_t)blockIdx.x * 4 + (tid >> 6);
  const int s = l >> 4, li = l & 15;
  const int j0 = l * 8;
  const int c0 = li * 8;
  float kv[8], xv[8];
  {
    const float4 a = *reinterpret_cast<const float4*>(kraw + i * 512 + j0);
    const float4 b = *reinterpret_cast<const float4*>(kraw + i * 512 + j0 + 4);
    kv[0]=a.x; kv[1]=a.y; kv[2]=a.z; kv[3]=a.w; kv[4]=b.x; kv[5]=b.y; kv[6]=b.z; kv[7]=b.w;
  }
  {
    const float4 a = *reinterpret_cast<const float4*>(x + i * 512 + j0);
    const float4 b = *reinterpret_cast<const float4*>(x + i * 512 + j0 + 4);
    xv[0]=a.x; xv[1]=a.y; xv[2]=a.z; xv[3]=a.w; xv[4]=b.x; xv[5]=b.y; xv[6]=b.z; xv[7]=b.w;
  }
  float kb[8], nk[8], nq[8];
  {
    const float4 a = *reinterpret_cast<const float4*>(key_b + s * 128 + c0);
    const float4 b = *reinterpret_cast<const float4*>(key_b + s * 128 + c0 + 4);
    kb[0]=a.x; kb[1]=a.y; kb[2]=a.z; kb[3]=a.w; kb[4]=b.x; kb[5]=b.y; kb[6]=b.z; kb[7]=b.w;
  }
  {
    const float4 a = *reinterpret_cast<const float4*>(nk_w + s * 128 + c0);
    const float4 b = *reinterpret_cast<const float4*>(nk_w + s * 128 + c0 + 4);
    nk[0]=a.x; nk[1]=a.y; nk[2]=a.z; nk[3]=a.w; nk[4]=b.x; nk[5]=b.y; nk[6]=b.z; nk[7]=b.w;
  }
  {
    const float4 a = *reinterpret_cast<const float4*>(nq_w + s * 128 + c0);
    const float4 b = *reinterpret_cast<const float4*>(nq_w + s * 128 + c0 + 4);
    nq[0]=a.x; nq[1]=a.y; nq[2]=a.z; nq[3]=a.w; nq[4]=b.x; nq[5]=b.y; nq[6]=b.z; nq[7]=b.w;
  }
  float ssk = 0.f, ssx = 0.f;
#pragma unroll
  for (int jj = 0; jj < 8; ++jj) {
    kv[jj] += kb[jj];
    ssk = fmaf(kv[jj], kv[jj], ssk);
    ssx = fmaf(xv[jj], xv[jj], ssx);
  }
  ssk = red16(ssk);
  ssx = red16(ssx);
  const float invk = rsqrtf(ssk * (1.f / 128.f) + EPSF);
  const float invq = rsqrtf(ssx * (1.f / 128.f) + EPSF);
  float dot = 0.f;
#pragma unroll
  for (int jj = 0; jj < 8; ++jj)
    dot = fmaf(kv[jj] * invk * nk[jj], xv[jj] * invq * nq[jj], dot);
  dot = red16(dot);
  const float gate = sigm(dot * 0.08838834764831843f);
  const float2 vb2 = *reinterpret_cast<const float2*>(vbase + i * 128 + l * 2);
  float ssv = vb2.x * vb2.x + vb2.y * vb2.y;
  ssv = red64(ssv);
  const float A = gate * rsqrtf(gate * gate * (ssv * (1.f / 128.f)) + EPSF);
  if (li == 0) { gates[i * 4 + s] = gate; afac[i * 4 + s] = A; }
}

// ---------------------------------------------------------------------------
// engram conv + residual; ALSO emits inv-rms of the produced token (for mhc).
// ---------------------------------------------------------------------------
__global__ __launch_bounds__(256) void eng_conv(
    const float* __restrict__ x, const float* __restrict__ vbase,
    const float* __restrict__ gates, const float* __restrict__ afac,
    const float* __restrict__ conv_w, const float* __restrict__ cnw,
    float* __restrict__ xout, float* __restrict__ invout)
{
  const size_t i = blockIdx.x;
  const int tt = (int)(i & 127);
  const int tid = threadIdx.x;
  __shared__ float sA[4][4];
  __shared__ float sG[4];
  __shared__ float part[4];
  if (tid < 16) {
    const int kk = tid >> 2, s = tid & 3;
    const int t2 = tt - 3 + kk;
    sA[kk][s] = (t2 >= 0) ? afac[(i - 3 + kk) * 4 + s] : 0.f;
  } else if (tid < 20) {
    sG[tid - 16] = gates[i * 4 + (tid - 16)];
  }
  __syncthreads();
  float ssq = 0.f;
#pragma unroll
  for (int p = 0; p < 2; ++p) {
    const int j = tid + p * 256;
    const int s = j >> 7, c = j & 127;
    const float4 cw = *reinterpret_cast<const float4*>(conv_w + (size_t)j * 4);
    float accv = 0.f;
#pragma unroll
    for (int kk = 0; kk < 4; ++kk) {
      const int t2 = tt - 3 + kk;
      const float vb = (t2 >= 0) ? vbase[(i - 3 + kk) * 128 + c] : 0.f;
      const float wv = (kk == 0) ? cw.x : (kk == 1) ? cw.y : (kk == 2) ? cw.z : cw.w;
      accv = fmaf(vb * sA[kk][s], wv, accv);
    }
    const float yv = accv * cnw[s * 128 + c];
    const float sil = yv * sigm(yv);
    const float o = x[i * 512 + j] + vbase[i * 128 + c] * sG[s] + sil;
    xout[i * 512 + j] = o;
    ssq = fmaf(o, o, ssq);
  }
  ssq = red64(ssq);
  if ((tid & 63) == 0) part[tid >> 6] = ssq;
  __syncthreads();
  if (tid == 0)
    invout[i] = rsqrtf((part[0] + part[1] + part[2] + part[3]) * (1.f / 512.f) + EPSF);
}

// ---------------------------------------------------------------------------
// mhc sink: per token (1 wave): proj[32] -> H_pre/H_post/sinkhorn; x_agg +
// rmsnorm128 -> xa ; stores hres(16), hps(1).
// proj cols: 0-15 res(+b), 16-19 pre(+b), 20-23 post(+b).
// ---------------------------------------------------------------------------
__global__ __launch_bounds__(256) void mhc_sink(
    const float* __restrict__ proj, const float* __restrict__ xin,
    const float* __restrict__ p_apre, const float* __restrict__ p_apost,
    const float* __restrict__ p_ares, const float* __restrict__ ln_w,
    float* __restrict__ xa, float* __restrict__ hres, float* __restrict__ hps)
{
  const int tid = threadIdx.x;
  const int l = tid & 63;
  const size_t i = (size_t)blockIdx.x * 4 + (tid >> 6);
  const float pv = proj[i * 32 + (l & 31)];
  const float apre = p_apre[0], apost = p_apost[0], ares = p_ares[0];
  const int n = l >> 4;
  const float hp = sigm(apre * __shfl(pv, 16 + n));
  float hsum = 0.f;
#pragma unroll
  for (int t2 = 0; t2 < 4; ++t2) hsum += 2.f * sigm(apost * __shfl(pv, 20 + t2));
  // sinkhorn (lanes l&31 < 16 hold res elements; element (li>>2, li&3))
  const float v = ares * pv;
  float rm = fmaxf(v, __shfl_xor(v, 1));
  rm = fmaxf(rm, __shfl_xor(rm, 2));
  float m = __expf(v - rm);
#pragma unroll
  for (int it = 0; it < 20; ++it) {
    float rs = m + __shfl_xor(m, 1);
    rs += __shfl_xor(rs, 2);
    m *= __builtin_amdgcn_rcpf(rs + 1e-6f);
    float cs = m + __shfl_xor(m, 4);
    cs += __shfl_xor(cs, 8);
    m *= __builtin_amdgcn_rcpf(cs + 1e-6f);
  }
  if (l < 16) hres[i * 16 + l] = m;
  if (l == 0) hps[i] = hsum;
  // x_agg
  const int j0 = l * 8;
  float xv[8];
  {
    const float4 a = *reinterpret_cast<const float4*>(xin + i * 512 + j0);
    const float4 b = *reinterpret_cast<const float4*>(xin + i * 512 + j0 + 4);
    xv[0]=a.x; xv[1]=a.y; xv[2]=a.z; xv[3]=a.w; xv[4]=b.x; xv[5]=b.y; xv[6]=b.z; xv[7]=b.w;
  }
  float ag[8];
#pragma unroll
  for (int jj = 0; jj < 8; ++jj) {
    float a2 = hp * xv[jj];
    a2 += __shfl_xor(a2, 16);
    a2 += __shfl_xor(a2, 32);
    ag[jj] = a2;
  }
  float ssa = 0.f;
#pragma unroll
  for (int jj = 0; jj < 8; ++jj) ssa = fmaf(ag[jj], ag[jj], ssa);
  ssa = red16(ssa);
  const float inva = rsqrtf(ssa * (1.f / 128.f) + EPSF);
  if (l < 16) {
    const int c0 = l * 8;
    const float4 wa = *reinterpret_cast<const float4*>(ln_w + c0);
    const float4 wb = *reinterpret_cast<const float4*>(ln_w + c0 + 4);
    const float4 o1 = make_float4(ag[0]*inva*wa.x, ag[1]*inva*wa.y, ag[2]*inva*wa.z, ag[3]*inva*wa.w);
    const float4 o2 = make_float4(ag[4]*inva*wb.x, ag[5]*inva*wb.y, ag[6]*inva*wb.z, ag[7]*inva*wb.w);
    *reinterpret_cast<float4*>(xa + i * 128 + c0) = o1;
    *reinterpret_cast<float4*>(xa + i * 128 + c0 + 4) = o2;
  }
}

// ---------------------------------------------------------------------------
// causal attention per (b,h): T=128, D=32 (unchanged from R1)
// ---------------------------------------------------------------------------
__global__ __launch_bounds__(256) void attn_kern(
    const float* __restrict__ qkv, float* __restrict__ y)
{
  __shared__ float Qs[128][36];
  __shared__ float Ks[128][36];
  __shared__ float Vs[128][36];
  const int tid = threadIdx.x;
  const int b = blockIdx.x >> 2, h = blockIdx.x & 3;
  const float* __restrict__ src0 = qkv + (size_t)b * 128 * 384 + h * 32;
#pragma unroll
  for (int p = 0; p < 4; ++p) {
    const int idx = p * 256 + tid;
    const int row = idx >> 3, f4 = (idx & 7) << 2;
    const float* s = src0 + (size_t)row * 384 + f4;
    *reinterpret_cast<float4*>(&Qs[row][f4]) = *reinterpret_cast<const float4*>(s);
    *reinterpret_cast<float4*>(&Ks[row][f4]) = *reinterpret_cast<const float4*>(s + 128);
    *reinterpret_cast<float4*>(&Vs[row][f4]) = *reinterpret_cast<const float4*>(s + 256);
  }
  __syncthreads();
  const int rbase = tid >> 2;
  const int s0 = (tid & 3) << 5;
  const float scl = 0.17677669529663687f;
  for (int half = 0; half < 2; ++half) {
    const int row = rbase + half * 64;
    float4 q4[8];
#pragma unroll
    for (int dd = 0; dd < 8; ++dd) q4[dd] = *reinterpret_cast<const float4*>(&Qs[row][dd << 2]);
    float sc[32];
    float mx = -3.4e38f;
#pragma unroll
    for (int is = 0; is < 32; ++is) {
      const int s = s0 + is;
      float acc = 0.f;
#pragma unroll
      for (int dd = 0; dd < 8; ++dd)
        acc = dot4(q4[dd], *reinterpret_cast<const float4*>(&Ks[s][dd << 2]), acc);
      if (s <= row) { sc[is] = acc * scl; mx = fmaxf(mx, sc[is]); }
      else sc[is] = 0.f;
    }
    mx = fmaxf(mx, __shfl_xor(mx, 1));
    mx = fmaxf(mx, __shfl_xor(mx, 2));
    float sum = 0.f;
#pragma unroll
    for (int is = 0; is < 32; ++is) {
      const float p = (s0 + is <= row) ? __expf(sc[is] - mx) : 0.f;
      sc[is] = p;
      sum += p;
    }
    sum += __shfl_xor(sum, 1);
    sum += __shfl_xor(sum, 2);
    const float rinv = 1.f / sum;
    float4 ac[8];
#pragma unroll
    for (int dd = 0; dd < 8; ++dd) ac[dd] = make_float4(0.f, 0.f, 0.f, 0.f);
#pragma unroll
    for (int is = 0; is < 32; ++is) {
      const float p = sc[is];
      const int s = s0 + is;
#pragma unroll
      for (int dd = 0; dd < 8; ++dd)
        fma4(ac[dd], p, *reinterpret_cast<const float4*>(&Vs[s][dd << 2]));
    }
#pragma unroll
    for (int dd = 0; dd < 8; ++dd) {
      ac[dd].x += __shfl_xor(ac[dd].x, 1); ac[dd].x += __shfl_xor(ac[dd].x, 2);
      ac[dd].y += __shfl_xor(ac[dd].y, 1); ac[dd].y += __shfl_xor(ac[dd].y, 2);
      ac[dd].z += __shfl_xor(ac[dd].z, 1); ac[dd].z += __shfl_xor(ac[dd].z, 2);
      ac[dd].w += __shfl_xor(ac[dd].w, 1); ac[dd].w += __shfl_xor(ac[dd].w, 2);
    }
    if ((tid & 3) == 0) {
      float* dst = y + ((size_t)b * 128 + row) * 128 + h * 32;
#pragma unroll
      for (int dd = 0; dd < 8; ++dd) {
        const float4 o = make_float4(ac[dd].x * rinv, ac[dd].y * rinv,
                                     ac[dd].z * rinv, ac[dd].w * rinv);
        *reinterpret_cast<float4*>(dst + (dd << 2)) = o;
      }
    }
  }
}

// ---------------------------------------------------------------------------
// mhc combine; ALSO emits inv-rms of the produced token (for next mhc head).
// ---------------------------------------------------------------------------
__global__ __launch_bounds__(128) void mhc_combine(
    const float* __restrict__ xst, const float* __restrict__ hres,
    const float* __restrict__ hps, const float* __restrict__ yv,
    float* __restrict__ out, float* __restrict__ invout)
{
  const size_t i = blockIdx.x;
  const int c = threadIdx.x;
  __shared__ float H[16];
  __shared__ float g;
  __shared__ float part[2];
  if (c < 16) H[c] = hres[i * 16 + c];
  if (c == 16) g = hps[i];
  __syncthreads();
  const float x0 = xst[i * 512 + c];
  const float x1 = xst[i * 512 + 128 + c];
  const float x2 = xst[i * 512 + 256 + c];
  const float x3 = xst[i * 512 + 384 + c];
  const float yb = g * yv[i * 128 + c];
  const float o0 = H[0]  * x0 + H[1]  * x1 + H[2]  * x2 + H[3]  * x3 + yb;
  const float o1 = H[4]  * x0 + H[5]  * x1 + H[6]  * x2 + H[7]  * x3 + yb;
  const float o2 = H[8]  * x0 + H[9]  * x1 + H[10] * x2 + H[11] * x3 + yb;
  const float o3 = H[12] * x0 + H[13] * x1 + H[14] * x2 + H[15] * x3 + yb;
  out[i * 512 +       c] = o0;
  out[i * 512 + 128 + c] = o1;
  out[i * 512 + 256 + c] = o2;
  out[i * 512 + 384 + c] = o3;
  float ssq = o0 * o0 + o1 * o1 + o2 * o2 + o3 * o3;
  ssq = red64(ssq);
  if ((c & 63) == 0) part[c >> 6] = ssq;
  __syncthreads();
  if (c == 0) invout[i] = rsqrtf((part[0] + part[1]) * (1.f / 512.f) + EPSF);
}

// ---------------------------------------------------------------------------
extern "C" void kernel_launch(void* const* d_in, const int* in_sizes, int n_in,
                              void* d_out, int out_size, void* d_ws, size_t ws_size,
                              hipStream_t stream)
{
  const float* x        = (const float*)d_in[0];
  const int*   ids      = (const int*)d_in[1];
  const int*   mults    = (const int*)d_in[2];
  const float* table    = (const float*)d_in[3];
  const float* val_w    = (const float*)d_in[4];
  const float* val_b    = (const float*)d_in[5];
  const float* key_w    = (const float*)d_in[6];
  const float* key_b    = (const float*)d_in[7];
  const float* nq_w     = (const float*)d_in[8];
  const float* nk_w     = (const float*)d_in[9];
  const float* conv_w   = (const float*)d_in[10];
  const float* cnw      = (const float*)d_in[11];
  const float* a_coef   = (const float*)d_in[12];
  const float* a_pre_w  = (const float*)d_in[13];
  const float* a_pre_b  = (const float*)d_in[14];
  const float* a_post_w = (const float*)d_in[15];
  const float* a_post_b = (const float*)d_in[16];
  const float* a_res_w  = (const float*)d_in[17];
  const float* a_res_b  = (const float*)d_in[18];
  const float* a_apre   = (const float*)d_in[19];
  const float* a_apost  = (const float*)d_in[20];
  const float* a_ares   = (const float*)d_in[21];
  const float* a_ln_w   = (const float*)d_in[22];
  const float* qkv_w    = (const float*)d_in[23];
  const float* qkv_b    = (const float*)d_in[24];
  const float* proj_w   = (const float*)d_in[25];
  const float* proj_b   = (const float*)d_in[26];
  const float* m_coef   = (const float*)d_in[27];
  const float* m_pre_w  = (const float*)d_in[28];
  const float* m_pre_b  = (const float*)d_in[29];
  const float* m_post_w = (const float*)d_in[30];
  const float* m_post_b = (const float*)d_in[31];
  const float* m_res_w  = (const float*)d_in[32];
  const float* m_res_b  = (const float*)d_in[33];
  const float* m_apre   = (const float*)d_in[34];
  const float* m_apost  = (const float*)d_in[35];
  const float* m_ares   = (const float*)d_in[36];
  const float* m_ln_w   = (const float*)d_in[37];
  const float* mlp_w1   = (const float*)d_in[38];
  const float* mlp_b1   = (const float*)d_in[39];
  const float* mlp_w2   = (const float*)d_in[40];
  const float* mlp_b2   = (const float*)d_in[41];

  float* out = (float*)d_out;
  float* ws  = (float*)d_ws;
  float* vbase = ws;                        // BT*128
  float* kraw  = vbase + (size_t)BT * 128;  // BT*512 (k_raw -> qkv -> x2)
  float* gates = kraw  + (size_t)BT * 512;  // BT*4
  float* afac  = gates + (size_t)BT * 4;    // BT*4
  float* xa    = afac  + (size_t)BT * 4;    // BT*128
  float* y1    = xa    + (size_t)BT * 128;  // BT*128 (proj24 overlay / attn out)
  float* y2    = y1    + (size_t)BT * 128;  // BT*128
  float* hresb = y2    + (size_t)BT * 128;  // BT*16
  float* hpsb  = hresb + (size_t)BT * 16;   // BT
  float* inv1  = hpsb  + (size_t)BT;        // BT
  float* inv2  = inv1  + (size_t)BT;        // BT
  float* bpk_a = inv2  + (size_t)BT;        // 32
  float* bpk_m = bpk_a + 32;                // 32
  short* wt_qkv  = (short*)(bpk_m + 32);    // 384*128
  short* wt_proj = wt_qkv  + 49152;         // 128*128
  short* wt_mlp1 = wt_proj + 16384;         // 512*128
  short* wt_mlp2 = wt_mlp1 + 65536;         // 128*512
  short* wt_eng  = wt_mlp2 + 65536;         // 640*256
  short* wpk_a   = wt_eng  + 163840;        // 32*512
  short* wpk_m   = wpk_a   + 16384;         // 32*512
  float* proj24  = y1;                      // BT*32 overlay

  prep<<<1537, 256, 0, stream>>>(qkv_w, proj_w, mlp_w1, mlp_w2, val_w, key_w,
                                 a_res_w, a_pre_w, a_post_w, m_res_w, m_pre_w, m_post_w,
                                 a_res_b, a_pre_b, a_post_b, m_res_b, m_pre_b, m_post_b,
                                 wt_qkv, wt_proj, wt_mlp1, wt_mlp2, wt_eng,
                                 wpk_a, wpk_m, bpk_a, bpk_m);

  // ---- engram ----
  eng_mgemm<<<dim3(BT / 128, 5), 256, 0, stream>>>(ids, mults, table, val_b, wt_eng,
                                                   vbase, kraw);
  eng_gate<<<BT / 4, 256, 0, stream>>>(kraw, x, vbase, key_b, nk_w, nq_w, gates, afac);
  eng_conv<<<BT, 256, 0, stream>>>(x, vbase, gates, afac, conv_w, cnw, out, inv1);

  // ---- mhc (attention) ----
  mgemm32<<<BT / 128, 256, 0, stream>>>(out, 512, wpk_a, bpk_a, proj24, 512, inv1, a_coef);
  mhc_sink<<<BT / 4, 256, 0, stream>>>(proj24, out, a_apre, a_apost, a_ares, a_ln_w,
                                       xa, hresb, hpsb);
  mgemm<0, false><<<dim3(BT / 128, 3), 256, 0, stream>>>(xa, 128, wt_qkv, qkv_b,
                                                         kraw, 384, 128, nullptr, nullptr);
  attn_kern<<<1024, 256, 0, stream>>>(kraw, y1);
  mgemm<0, false><<<dim3(BT / 128, 1), 256, 0, stream>>>(y1, 128, wt_proj, proj_b,
                                                         y2, 128, 128, nullptr, nullptr);
  mhc_combine<<<BT, 128, 0, stream>>>(out, hresb, hpsb, y2, kraw, inv2);

  // ---- mhc (mlp) ----
  mgemm32<<<BT / 128, 256, 0, stream>>>(kraw, 512, wpk_m, bpk_m, proj24, 512, inv2, m_coef);
  mhc_sink<<<BT / 4, 256, 0, stream>>>(proj24, kraw, m_apre, m_apost, m_ares, m_ln_w,
                                       xa, hresb, hpsb);
  mgemm<1, false><<<dim3(BT / 128, 4), 256, 0, stream>>>(xa, 128, wt_mlp1, mlp_b1,
                                                         out, 512, 128, nullptr, nullptr);
  mgemm<0, false><<<dim3(BT / 128, 1), 256, 0, stream>>>(out, 512, wt_mlp2, mlp_b2,
                                                         y2, 128, 512, nullptr, nullptr);
  mhc_combine<<<BT, 128, 0, stream>>>(kraw, hresb, hpsb, y2, out, inv1);

  (void)in_sizes; (void)n_in; (void)out_size; (void)ws_size;
}

// Round 3
// 390.498 us; speedup vs baseline: 2.2663x; 1.2008x over previous
//
#include <hip/hip_runtime.h>

#define BT 32768
#define TSEQ 128

constexpr float EPSF = 1.1920929e-07f;

typedef __attribute__((ext_vector_type(8))) short bf16x8;
typedef __attribute__((ext_vector_type(4))) float f32x4;

__device__ __forceinline__ float sigm(float z) { return 1.f / (1.f + __expf(-z)); }

__device__ __forceinline__ short bf16c(float f) {
  union { float f; unsigned u; } v; v.f = f;
  unsigned r = v.u + 0x7FFFu + ((v.u >> 16) & 1u);
  return (short)(r >> 16);
}

__device__ __forceinline__ float red64(float v) {
  v += __shfl_xor(v, 1);  v += __shfl_xor(v, 2);  v += __shfl_xor(v, 4);
  v += __shfl_xor(v, 8);  v += __shfl_xor(v, 16); v += __shfl_xor(v, 32);
  return v;
}
__device__ __forceinline__ float red16(float v) {
  v += __shfl_xor(v, 1); v += __shfl_xor(v, 2); v += __shfl_xor(v, 4); v += __shfl_xor(v, 8);
  return v;
}
__device__ __forceinline__ float redmax16(float v) {
  v = fmaxf(v, __shfl_xor(v, 1)); v = fmaxf(v, __shfl_xor(v, 2));
  v = fmaxf(v, __shfl_xor(v, 4)); v = fmaxf(v, __shfl_xor(v, 8));
  return v;
}

// ---------------------------------------------------------------------------
// prep: build bf16 transposed weights [N][K] + packed mhc weights/biases.
// ---------------------------------------------------------------------------
__global__ __launch_bounds__(256) void prep(
    const float* __restrict__ qkv_w, const float* __restrict__ proj_w,
    const float* __restrict__ mlp_w1, const float* __restrict__ mlp_w2,
    const float* __restrict__ val_w, const float* __restrict__ key_w,
    const float* __restrict__ a_res_w, const float* __restrict__ a_pre_w,
    const float* __restrict__ a_post_w,
    const float* __restrict__ m_res_w, const float* __restrict__ m_pre_w,
    const float* __restrict__ m_post_w,
    const float* __restrict__ a_res_b, const float* __restrict__ a_pre_b,
    const float* __restrict__ a_post_b,
    const float* __restrict__ m_res_b, const float* __restrict__ m_pre_b,
    const float* __restrict__ m_post_b,
    short* __restrict__ wt_qkv, short* __restrict__ wt_proj,
    short* __restrict__ wt_mlp1, short* __restrict__ wt_mlp2,
    short* __restrict__ wt_eng, short* __restrict__ wpk_a,
    short* __restrict__ wpk_m, float* __restrict__ bpk_a,
    float* __restrict__ bpk_m)
{
  const int idx = blockIdx.x * 256 + threadIdx.x;
  if (idx < 49152) {
    const int n = idx >> 7, k = idx & 127;
    wt_qkv[idx] = bf16c(qkv_w[k * 384 + n]);
  } else if (idx < 65536) {
    const int j = idx - 49152; const int n = j >> 7, k = j & 127;
    wt_proj[j] = bf16c(proj_w[k * 128 + n]);
  } else if (idx < 131072) {
    const int j = idx - 65536; const int n = j >> 7, k = j & 127;
    wt_mlp1[j] = bf16c(mlp_w1[k * 512 + n]);
  } else if (idx < 196608) {
    const int j = idx - 131072; const int n = j >> 9, k = j & 511;
    wt_mlp2[j] = bf16c(mlp_w2[k * 128 + n]);
  } else if (idx < 360448) {
    const int j = idx - 196608; const int n = j >> 8, k = j & 255;
    float v;
    if (n < 128) v = val_w[k * 128 + n];
    else v = key_w[(size_t)((n - 128) >> 7) * 32768 + k * 128 + (n & 127)];
    wt_eng[j] = bf16c(v);
  } else if (idx < 376832) {
    const int j = idx - 360448; const int r = j >> 9, k = j & 511;
    float v = 0.f;
    if (r < 16) v = a_res_w[k * 16 + r];
    else if (r < 20) v = a_pre_w[k * 4 + (r - 16)];
    else if (r < 24) v = a_post_w[k * 4 + (r - 20)];
    wpk_a[j] = bf16c(v);
  } else if (idx < 393216) {
    const int j = idx - 376832; const int r = j >> 9, k = j & 511;
    float v = 0.f;
    if (r < 16) v = m_res_w[k * 16 + r];
    else if (r < 20) v = m_pre_w[k * 4 + (r - 16)];
    else if (r < 24) v = m_post_w[k * 4 + (r - 20)];
    wpk_m[j] = bf16c(v);
  } else if (idx < 393280) {
    const int j = idx - 393216;
    if (j < 32) {
      float v = 0.f;
      if (j < 16) v = a_res_b[j];
      else if (j < 20) v = a_pre_b[j - 16];
      else if (j < 24) v = a_post_b[j - 20];
      bpk_a[j] = v;
    } else {
      const int r = j - 32;
      float v = 0.f;
      if (r < 16) v = m_res_b[r];
      else if (r < 20) v = m_pre_b[r - 16];
      else if (r < 24) v = m_post_b[r - 20];
      bpk_m[r] = v;
    }
  }
}

// ---------------------------------------------------------------------------
// MFMA GEMM: out[M x N](f32) = act(A[M x K](f32) @ WT^T + bias)
// WT is bf16 [N][K] row-major. Tile 128x128, BK=64, 4 waves (2x2 of 64x64).
// ---------------------------------------------------------------------------
template <int ACT, bool SCALED>
__global__ __launch_bounds__(256) void mgemm(
    const float* __restrict__ A, const int lda,
    const short* __restrict__ WT, const float* __restrict__ bias,
    float* __restrict__ out, const int ldo, const int K,
    const float* __restrict__ rinv, const float* __restrict__ csc)
{
  __shared__ short As[128 * 64];
  __shared__ short Bs[128 * 64];
  const int tid = threadIdx.x;
  const int i0 = blockIdx.x * 128;
  const int c0 = blockIdx.y * 128;
  const int w = tid >> 6, l = tid & 63;
  const int wr = (w >> 1) * 64, wc = (w & 1) * 64;
  f32x4 acc[4][4];
#pragma unroll
  for (int mi = 0; mi < 4; ++mi)
#pragma unroll
    for (int ni = 0; ni < 4; ++ni) acc[mi][ni] = {0.f, 0.f, 0.f, 0.f};

  const int c4 = tid & 15;
  const int asl = c4 >> 1, ahf = c4 & 1;
  const int bsl = tid & 7;

  for (int kc = 0; kc < K; kc += 64) {
    __syncthreads();
#pragma unroll
    for (int p = 0; p < 8; ++p) {
      const int r = (tid >> 4) + p * 16;
      float4 v = *reinterpret_cast<const float4*>(A + (size_t)(i0 + r) * lda + kc + c4 * 4);
      if (SCALED) {
        const float rs = rinv[i0 + r];
        const float4 cs = *reinterpret_cast<const float4*>(csc + kc + c4 * 4);
        v.x *= rs * cs.x; v.y *= rs * cs.y; v.z *= rs * cs.z; v.w *= rs * cs.w;
      }
      short4 b4; b4.x = bf16c(v.x); b4.y = bf16c(v.y); b4.z = bf16c(v.z); b4.w = bf16c(v.w);
      *reinterpret_cast<short4*>(&As[r * 64 + ((asl ^ (r & 7)) << 3) + (ahf << 2)]) = b4;
    }
#pragma unroll
    for (int p = 0; p < 4; ++p) {
      const int r = (tid >> 3) + p * 32;
      const bf16x8 v = *reinterpret_cast<const bf16x8*>(WT + (size_t)(c0 + r) * K + kc + bsl * 8);
      *reinterpret_cast<bf16x8*>(&Bs[r * 64 + ((bsl ^ (r & 7)) << 3)]) = v;
    }
    __syncthreads();
    const int kg = l >> 4, lr = l & 15;
#pragma unroll
    for (int ks = 0; ks < 2; ++ks) {
      const int slot = ks * 4 + kg;
      bf16x8 af[4], bft[4];
#pragma unroll
      for (int mi = 0; mi < 4; ++mi) {
        const int r = wr + mi * 16 + lr;
        af[mi] = *reinterpret_cast<const bf16x8*>(&As[r * 64 + ((slot ^ (r & 7)) << 3)]);
      }
#pragma unroll
      for (int ni = 0; ni < 4; ++ni) {
        const int r = wc + ni * 16 + lr;
        bft[ni] = *reinterpret_cast<const bf16x8*>(&Bs[r * 64 + ((slot ^ (r & 7)) << 3)]);
      }
#pragma unroll
      for (int mi = 0; mi < 4; ++mi)
#pragma unroll
        for (int ni = 0; ni < 4; ++ni)
          acc[mi][ni] = __builtin_amdgcn_mfma_f32_16x16x32_bf16(af[mi], bft[ni], acc[mi][ni], 0, 0, 0);
    }
  }
  const int lr = l & 15, hi = l >> 4;
#pragma unroll
  for (int mi = 0; mi < 4; ++mi)
#pragma unroll
    for (int ni = 0; ni < 4; ++ni) {
      const int col = c0 + wc + ni * 16 + lr;
      const float bv = bias[col];
#pragma unroll
      for (int j = 0; j < 4; ++j) {
        const int row = i0 + wr + mi * 16 + hi * 4 + j;
        float o = acc[mi][ni][j] + bv;
        if (ACT == 1) o = o * sigm(o);
        out[(size_t)row * ldo + col] = o;
      }
    }
}

// ---------------------------------------------------------------------------
// MFMA GEMM, N=32 (mhc projection). Tile 128x32, BK=64, 4 waves (32 rows ea).
// ---------------------------------------------------------------------------
__global__ __launch_bounds__(256) void mgemm32(
    const float* __restrict__ A, const int lda,
    const short* __restrict__ WT, const float* __restrict__ bias,
    float* __restrict__ out, const int K,
    const float* __restrict__ rinv, const float* __restrict__ csc)
{
  __shared__ short As[128 * 64];
  __shared__ short Bs[32 * 64];
  const int tid = threadIdx.x;
  const int i0 = blockIdx.x * 128;
  const int w = tid >> 6, l = tid & 63;
  const int wr = w * 32;
  f32x4 acc[2][2];
#pragma unroll
  for (int mi = 0; mi < 2; ++mi)
#pragma unroll
    for (int ni = 0; ni < 2; ++ni) acc[mi][ni] = {0.f, 0.f, 0.f, 0.f};

  const int c4 = tid & 15;
  const int asl = c4 >> 1, ahf = c4 & 1;

  for (int kc = 0; kc < K; kc += 64) {
    __syncthreads();
#pragma unroll
    for (int p = 0; p < 8; ++p) {
      const int r = (tid >> 4) + p * 16;
      float4 v = *reinterpret_cast<const float4*>(A + (size_t)(i0 + r) * lda + kc + c4 * 4);
      const float rs = rinv[i0 + r];
      const float4 cs = *reinterpret_cast<const float4*>(csc + kc + c4 * 4);
      v.x *= rs * cs.x; v.y *= rs * cs.y; v.z *= rs * cs.z; v.w *= rs * cs.w;
      short4 b4; b4.x = bf16c(v.x); b4.y = bf16c(v.y); b4.z = bf16c(v.z); b4.w = bf16c(v.w);
      *reinterpret_cast<short4*>(&As[r * 64 + ((asl ^ (r & 7)) << 3) + (ahf << 2)]) = b4;
    }
    {
      const int r = tid >> 3, slb = tid & 7;
      const bf16x8 v = *reinterpret_cast<const bf16x8*>(WT + (size_t)r * K + kc + slb * 8);
      *reinterpret_cast<bf16x8*>(&Bs[r * 64 + ((slb ^ (r & 7)) << 3)]) = v;
    }
    __syncthreads();
    const int kg = l >> 4, lr = l & 15;
#pragma unroll
    for (int ks = 0; ks < 2; ++ks) {
      const int slot = ks * 4 + kg;
      bf16x8 af[2], bft[2];
#pragma unroll
      for (int mi = 0; mi < 2; ++mi) {
        const int r = wr + mi * 16 + lr;
        af[mi] = *reinterpret_cast<const bf16x8*>(&As[r * 64 + ((slot ^ (r & 7)) << 3)]);
      }
#pragma unroll
      for (int ni = 0; ni < 2; ++ni) {
        const int r = ni * 16 + lr;
        bft[ni] = *reinterpret_cast<const bf16x8*>(&Bs[r * 64 + ((slot ^ (r & 7)) << 3)]);
      }
#pragma unroll
      for (int mi = 0; mi < 2; ++mi)
#pragma unroll
        for (int ni = 0; ni < 2; ++ni)
          acc[mi][ni] = __builtin_amdgcn_mfma_f32_16x16x32_bf16(af[mi], bft[ni], acc[mi][ni], 0, 0, 0);
    }
  }
  const int lr = l & 15, hi = l >> 4;
#pragma unroll
  for (int mi = 0; mi < 2; ++mi)
#pragma unroll
    for (int ni = 0; ni < 2; ++ni) {
      const int col = ni * 16 + lr;
      const float bv = bias[col];
#pragma unroll
      for (int j = 0; j < 4; ++j) {
        const int row = i0 + wr + mi * 16 + hi * 4 + j;
        out[(size_t)row * 32 + col] = acc[mi][ni][j] + bv;
      }
    }
}

// ---------------------------------------------------------------------------
// engram MFMA GEMM: ngram-hash + embedding gather fused into A staging.
// ---------------------------------------------------------------------------
__global__ __launch_bounds__(256) void eng_mgemm(
    const int* __restrict__ ids, const int* __restrict__ mults,
    const float* __restrict__ table, const float* __restrict__ val_b,
    const short* __restrict__ wt_eng,
    float* __restrict__ vbase, float* __restrict__ kraw)
{
  __shared__ int hid[128][4];
  __shared__ short As[128 * 64];
  __shared__ short Bs[128 * 64];
  const int tid = threadIdx.x;
  const int i0 = blockIdx.x * 128;
  const int by = blockIdx.y;
  const int c0 = by * 128;
#pragma unroll
  for (int p = 0; p < 2; ++p) {
    const int idx = tid + p * 256;
    const int r = idx >> 2, wh = idx & 3;
    const int i = i0 + r;
    const int b = i >> 7, tt = i & 127;
    const int* __restrict__ row = ids + b * TSEQ;
    const int g2 = row[tt];
    const int g1 = (tt >= 1) ? row[tt - 1] : 0;
    const int g0 = (tt >= 2) ? row[tt - 2] : 0;
    int h;
    if (wh == 0)      h = ((g1 * mults[0]) ^ (g2 * mults[1])) & 4095;
    else if (wh == 1) h = (((g1 * mults[3]) ^ (g2 * mults[4])) & 4095) + 4096;
    else if (wh == 2) h = (((g0 * mults[6]) ^ (g1 * mults[7]) ^ (g2 * mults[8])) & 4095) + 8192;
    else              h = (((g0 * mults[9]) ^ (g1 * mults[10]) ^ (g2 * mults[11])) & 4095) + 12288;
    hid[r][wh] = h;
  }
  const int w = tid >> 6, l = tid & 63;
  const int wr = (w >> 1) * 64, wc = (w & 1) * 64;
  f32x4 acc[4][4];
#pragma unroll
  for (int mi = 0; mi < 4; ++mi)
#pragma unroll
    for (int ni = 0; ni < 4; ++ni) acc[mi][ni] = {0.f, 0.f, 0.f, 0.f};

  const int c4 = tid & 15;
  const int asl = c4 >> 1, ahf = c4 & 1;
  const int bsl = tid & 7;

  for (int kc = 0; kc < 256; kc += 64) {
    const int seg = kc >> 6;
    __syncthreads();
#pragma unroll
    for (int p = 0; p < 8; ++p) {
      const int r = (tid >> 4) + p * 16;
      const float4 v = *reinterpret_cast<const float4*>(table + (size_t)hid[r][seg] * 64 + c4 * 4);
      short4 b4; b4.x = bf16c(v.x); b4.y = bf16c(v.y); b4.z = bf16c(v.z); b4.w = bf16c(v.w);
      *reinterpret_cast<short4*>(&As[r * 64 + ((asl ^ (r & 7)) << 3) + (ahf << 2)]) = b4;
    }
#pragma unroll
    for (int p = 0; p < 4; ++p) {
      const int r = (tid >> 3) + p * 32;
      const bf16x8 v = *reinterpret_cast<const bf16x8*>(wt_eng + (size_t)(c0 + r) * 256 + kc + bsl * 8);
      *reinterpret_cast<bf16x8*>(&Bs[r * 64 + ((bsl ^ (r & 7)) << 3)]) = v;
    }
    __syncthreads();
    const int kg = l >> 4, lr = l & 15;
#pragma unroll
    for (int ks = 0; ks < 2; ++ks) {
      const int slot = ks * 4 + kg;
      bf16x8 af[4], bft[4];
#pragma unroll
      for (int mi = 0; mi < 4; ++mi) {
        const int r = wr + mi * 16 + lr;
        af[mi] = *reinterpret_cast<const bf16x8*>(&As[r * 64 + ((slot ^ (r & 7)) << 3)]);
      }
#pragma unroll
      for (int ni = 0; ni < 4; ++ni) {
        const int r = wc + ni * 16 + lr;
        bft[ni] = *reinterpret_cast<const bf16x8*>(&Bs[r * 64 + ((slot ^ (r & 7)) << 3)]);
      }
#pragma unroll
      for (int mi = 0; mi < 4; ++mi)
#pragma unroll
        for (int ni = 0; ni < 4; ++ni)
          acc[mi][ni] = __builtin_amdgcn_mfma_f32_16x16x32_bf16(af[mi], bft[ni], acc[mi][ni], 0, 0, 0);
    }
  }
  const int lr = l & 15, hi = l >> 4;
#pragma unroll
  for (int mi = 0; mi < 4; ++mi)
#pragma unroll
    for (int ni = 0; ni < 4; ++ni) {
      const int col = wc + ni * 16 + lr;
#pragma unroll
      for (int j = 0; j < 4; ++j) {
        const int row = i0 + wr + mi * 16 + hi * 4 + j;
        if (by == 0)
          vbase[(size_t)row * 128 + col] = acc[mi][ni][j] + val_b[col];
        else
          kraw[(size_t)row * 512 + (by - 1) * 128 + col] = acc[mi][ni][j];
      }
    }
}

// ---------------------------------------------------------------------------
// engram gates (unchanged)
// ---------------------------------------------------------------------------
__global__ __launch_bounds__(256) void eng_gate(
    const float* __restrict__ kraw, const float* __restrict__ x,
    const float* __restrict__ vbase, const float* __restrict__ key_b,
    const float* __restrict__ nk_w, const float* __restrict__ nq_w,
    float* __restrict__ gates, float* __restrict__ afac)
{
  const int tid = threadIdx.x;
  const int l = tid & 63;
  const size_t i = (size_t)blockIdx.x * 4 + (tid >> 6);
  const int s = l >> 4, li = l & 15;
  const int j0 = l * 8;
  const int c0 = li * 8;
  float kv[8], xv[8];
  {
    const float4 a = *reinterpret_cast<const float4*>(kraw + i * 512 + j0);
    const float4 b = *reinterpret_cast<const float4*>(kraw + i * 512 + j0 + 4);
    kv[0]=a.x; kv[1]=a.y; kv[2]=a.z; kv[3]=a.w; kv[4]=b.x; kv[5]=b.y; kv[6]=b.z; kv[7]=b.w;
  }
  {
    const float4 a = *reinterpret_cast<const float4*>(x + i * 512 + j0);
    const float4 b = *reinterpret_cast<const float4*>(x + i * 512 + j0 + 4);
    xv[0]=a.x; xv[1]=a.y; xv[2]=a.z; xv[3]=a.w; xv[4]=b.x; xv[5]=b.y; xv[6]=b.z; xv[7]=b.w;
  }
  float kb[8], nk[8], nq[8];
  {
    const float4 a = *reinterpret_cast<const float4*>(key_b + s * 128 + c0);
    const float4 b = *reinterpret_cast<const float4*>(key_b + s * 128 + c0 + 4);
    kb[0]=a.x; kb[1]=a.y; kb[2]=a.z; kb[3]=a.w; kb[4]=b.x; kb[5]=b.y; kb[6]=b.z; kb[7]=b.w;
  }
  {
    const float4 a = *reinterpret_cast<const float4*>(nk_w + s * 128 + c0);
    const float4 b = *reinterpret_cast<const float4*>(nk_w + s * 128 + c0 + 4);
    nk[0]=a.x; nk[1]=a.y; nk[2]=a.z; nk[3]=a.w; nk[4]=b.x; nk[5]=b.y; nk[6]=b.z; nk[7]=b.w;
  }
  {
    const float4 a = *reinterpret_cast<const float4*>(nq_w + s * 128 + c0);
    const float4 b = *reinterpret_cast<const float4*>(nq_w + s * 128 + c0 + 4);
    nq[0]=a.x; nq[1]=a.y; nq[2]=a.z; nq[3]=a.w; nq[4]=b.x; nq[5]=b.y; nq[6]=b.z; nq[7]=b.w;
  }
  float ssk = 0.f, ssx = 0.f;
#pragma unroll
  for (int jj = 0; jj < 8; ++jj) {
    kv[jj] += kb[jj];
    ssk = fmaf(kv[jj], kv[jj], ssk);
    ssx = fmaf(xv[jj], xv[jj], ssx);
  }
  ssk = red16(ssk);
  ssx = red16(ssx);
  const float invk = rsqrtf(ssk * (1.f / 128.f) + EPSF);
  const float invq = rsqrtf(ssx * (1.f / 128.f) + EPSF);
  float dot = 0.f;
#pragma unroll
  for (int jj = 0; jj < 8; ++jj)
    dot = fmaf(kv[jj] * invk * nk[jj], xv[jj] * invq * nq[jj], dot);
  dot = red16(dot);
  const float gate = sigm(dot * 0.08838834764831843f);
  const float2 vb2 = *reinterpret_cast<const float2*>(vbase + i * 128 + l * 2);
  float ssv = vb2.x * vb2.x + vb2.y * vb2.y;
  ssv = red64(ssv);
  const float A = gate * rsqrtf(gate * gate * (ssv * (1.f / 128.f)) + EPSF);
  if (li == 0) { gates[i * 4 + s] = gate; afac[i * 4 + s] = A; }
}

// ---------------------------------------------------------------------------
// engram conv + residual; emits inv-rms of produced token.
// ---------------------------------------------------------------------------
__global__ __launch_bounds__(256) void eng_conv(
    const float* __restrict__ x, const float* __restrict__ vbase,
    const float* __restrict__ gates, const float* __restrict__ afac,
    const float* __restrict__ conv_w, const float* __restrict__ cnw,
    float* __restrict__ xout, float* __restrict__ invout)
{
  const size_t i = blockIdx.x;
  const int tt = (int)(i & 127);
  const int tid = threadIdx.x;
  __shared__ float sA[4][4];
  __shared__ float sG[4];
  __shared__ float part[4];
  if (tid < 16) {
    const int kk = tid >> 2, s = tid & 3;
    const int t2 = tt - 3 + kk;
    sA[kk][s] = (t2 >= 0) ? afac[(i - 3 + kk) * 4 + s] : 0.f;
  } else if (tid < 20) {
    sG[tid - 16] = gates[i * 4 + (tid - 16)];
  }
  __syncthreads();
  float ssq = 0.f;
#pragma unroll
  for (int p = 0; p < 2; ++p) {
    const int j = tid + p * 256;
    const int s = j >> 7, c = j & 127;
    const float4 cw = *reinterpret_cast<const float4*>(conv_w + (size_t)j * 4);
    float accv = 0.f;
#pragma unroll
    for (int kk = 0; kk < 4; ++kk) {
      const int t2 = tt - 3 + kk;
      const float vb = (t2 >= 0) ? vbase[(i - 3 + kk) * 128 + c] : 0.f;
      const float wv = (kk == 0) ? cw.x : (kk == 1) ? cw.y : (kk == 2) ? cw.z : cw.w;
      accv = fmaf(vb * sA[kk][s], wv, accv);
    }
    const float yv = accv * cnw[s * 128 + c];
    const float sil = yv * sigm(yv);
    const float o = x[i * 512 + j] + vbase[i * 128 + c] * sG[s] + sil;
    xout[i * 512 + j] = o;
    ssq = fmaf(o, o, ssq);
  }
  ssq = red64(ssq);
  if ((tid & 63) == 0) part[tid >> 6] = ssq;
  __syncthreads();
  if (tid == 0)
    invout[i] = rsqrtf((part[0] + part[1] + part[2] + part[3]) * (1.f / 512.f) + EPSF);
}

// ---------------------------------------------------------------------------
// mhc sink (unchanged)
// ---------------------------------------------------------------------------
__global__ __launch_bounds__(256) void mhc_sink(
    const float* __restrict__ proj, const float* __restrict__ xin,
    const float* __restrict__ p_apre, const float* __restrict__ p_apost,
    const float* __restrict__ p_ares, const float* __restrict__ ln_w,
    float* __restrict__ xa, float* __restrict__ hres, float* __restrict__ hps)
{
  const int tid = threadIdx.x;
  const int l = tid & 63;
  const size_t i = (size_t)blockIdx.x * 4 + (tid >> 6);
  const float pv = proj[i * 32 + (l & 31)];
  const float apre = p_apre[0], apost = p_apost[0], ares = p_ares[0];
  const int n = l >> 4;
  const float hp = sigm(apre * __shfl(pv, 16 + n));
  float hsum = 0.f;
#pragma unroll
  for (int t2 = 0; t2 < 4; ++t2) hsum += 2.f * sigm(apost * __shfl(pv, 20 + t2));
  const float v = ares * pv;
  float rm = fmaxf(v, __shfl_xor(v, 1));
  rm = fmaxf(rm, __shfl_xor(rm, 2));
  float m = __expf(v - rm);
#pragma unroll
  for (int it = 0; it < 20; ++it) {
    float rs = m + __shfl_xor(m, 1);
    rs += __shfl_xor(rs, 2);
    m *= __builtin_amdgcn_rcpf(rs + 1e-6f);
    float cs = m + __shfl_xor(m, 4);
    cs += __shfl_xor(cs, 8);
    m *= __builtin_amdgcn_rcpf(cs + 1e-6f);
  }
  if (l < 16) hres[i * 16 + l] = m;
  if (l == 0) hps[i] = hsum;
  const int j0 = l * 8;
  float xv[8];
  {
    const float4 a = *reinterpret_cast<const float4*>(xin + i * 512 + j0);
    const float4 b = *reinterpret_cast<const float4*>(xin + i * 512 + j0 + 4);
    xv[0]=a.x; xv[1]=a.y; xv[2]=a.z; xv[3]=a.w; xv[4]=b.x; xv[5]=b.y; xv[6]=b.z; xv[7]=b.w;
  }
  float ag[8];
#pragma unroll
  for (int jj = 0; jj < 8; ++jj) {
    float a2 = hp * xv[jj];
    a2 += __shfl_xor(a2, 16);
    a2 += __shfl_xor(a2, 32);
    ag[jj] = a2;
  }
  float ssa = 0.f;
#pragma unroll
  for (int jj = 0; jj < 8; ++jj) ssa = fmaf(ag[jj], ag[jj], ssa);
  ssa = red16(ssa);
  const float inva = rsqrtf(ssa * (1.f / 128.f) + EPSF);
  if (l < 16) {
    const int c0 = l * 8;
    const float4 wa = *reinterpret_cast<const float4*>(ln_w + c0);
    const float4 wb = *reinterpret_cast<const float4*>(ln_w + c0 + 4);
    const float4 o1 = make_float4(ag[0]*inva*wa.x, ag[1]*inva*wa.y, ag[2]*inva*wa.z, ag[3]*inva*wa.w);
    const float4 o2 = make_float4(ag[4]*inva*wb.x, ag[5]*inva*wb.y, ag[6]*inva*wb.z, ag[7]*inva*wb.w);
    *reinterpret_cast<float4*>(xa + i * 128 + c0) = o1;
    *reinterpret_cast<float4*>(xa + i * 128 + c0 + 4) = o2;
  }
}

// ---------------------------------------------------------------------------
// MFMA causal attention. Block = (b,h); 4 waves; wave w = q-strip [32w,32w+32).
// K bf16 LDS [128 s][32 d] chunk-swizzled; V bf16 transposed [32 d][128 s];
// P per-wave bf16 [32 r][128 s]. S/PV via mfma_f32_16x16x32_bf16.
// C-layout: col = l&15 (B side), row = 4*(l>>4)+j (A side)   [verified m89]
// A/B frag: row/col = l&15, k = 8*(l>>4)+j                    [matches mgemm]
// ---------------------------------------------------------------------------
__global__ __launch_bounds__(256) void attn_mfma(
    const float* __restrict__ qkv, float* __restrict__ y)
{
  __shared__ short Ks[128 * 32];      // 8KB, row=32 shorts, chunk=(c>>3)^((s>>1)&3)
  __shared__ short Vt[32 * 128];      // 8KB, row=128 shorts, chunk=(c>>3)^(d&7)
  __shared__ short Ps[4][32 * 128];   // 32KB, per wave
  const int tid = threadIdx.x;
  const int b = blockIdx.x >> 2, h = blockIdx.x & 3;
  const float* __restrict__ base = qkv + (size_t)b * 128 * 384 + h * 32;

  // stage K: 1024 float4 slots
#pragma unroll
  for (int p = 0; p < 4; ++p) {
    const int idx = tid + p * 256;
    const int s = idx >> 3, c4 = idx & 7;
    const float4 v = *reinterpret_cast<const float4*>(base + (size_t)s * 384 + 128 + c4 * 4);
    short4 o; o.x = bf16c(v.x); o.y = bf16c(v.y); o.z = bf16c(v.z); o.w = bf16c(v.w);
    const int chunk = (c4 >> 1) ^ ((s >> 1) & 3);
    *reinterpret_cast<short4*>(&Ks[s * 32 + chunk * 8 + (c4 & 1) * 4]) = o;
  }
  // stage V transposed
#pragma unroll
  for (int p = 0; p < 4; ++p) {
    const int idx = tid + p * 256;
    const int s = idx >> 3, c4 = idx & 7;
    const float4 v = *reinterpret_cast<const float4*>(base + (size_t)s * 384 + 256 + c4 * 4);
    const int schunk = s >> 3, soff = s & 7;
#pragma unroll
    for (int k = 0; k < 4; ++k) {
      const int d = c4 * 4 + k;
      const float vv = (k == 0) ? v.x : (k == 1) ? v.y : (k == 2) ? v.z : v.w;
      Vt[d * 128 + ((schunk ^ (d & 7)) << 3) + soff] = bf16c(vv);
    }
  }
  // Q A-frags from global
  const int w = tid >> 6, l = tid & 63;
  const int g = l >> 4, lr = l & 15;
  bf16x8 qa[2];
#pragma unroll
  for (int mi = 0; mi < 2; ++mi) {
    const int row = w * 32 + mi * 16 + lr;
    const float* qp = base + (size_t)row * 384 + g * 8;
    const float4 a = *reinterpret_cast<const float4*>(qp);
    const float4 c = *reinterpret_cast<const float4*>(qp + 4);
    bf16x8 q;
    q[0] = bf16c(a.x); q[1] = bf16c(a.y); q[2] = bf16c(a.z); q[3] = bf16c(a.w);
    q[4] = bf16c(c.x); q[5] = bf16c(c.y); q[6] = bf16c(c.z); q[7] = bf16c(c.w);
    qa[mi] = q;
  }
  __syncthreads();

  const int ntmax = 2 * w + 1;  // causal: cols <= 32w+31
  bf16x8 ka[8];
#pragma unroll
  for (int nt = 0; nt < 8; ++nt)
    if (nt <= ntmax) {
      const int s = nt * 16 + lr;
      const int chunk = g ^ ((s >> 1) & 3);
      ka[nt] = *reinterpret_cast<const bf16x8*>(&Ks[s * 32 + chunk * 8]);
    }
  f32x4 sacc[2][8];
#pragma unroll
  for (int mi = 0; mi < 2; ++mi)
#pragma unroll
    for (int nt = 0; nt < 8; ++nt) sacc[mi][nt] = {0.f, 0.f, 0.f, 0.f};
#pragma unroll
  for (int mi = 0; mi < 2; ++mi)
#pragma unroll
    for (int nt = 0; nt < 8; ++nt)
      if (nt <= ntmax)
        sacc[mi][nt] = __builtin_amdgcn_mfma_f32_16x16x32_bf16(qa[mi], ka[nt], sacc[mi][nt], 0, 0, 0);

  const float scl = 0.17677669529663687f; // 1/sqrt(32)
  float rv[2][4];
  short* const pw = Ps[w];
#pragma unroll
  for (int mi = 0; mi < 2; ++mi) {
#pragma unroll
    for (int j = 0; j < 4; ++j) {
      const int row = w * 32 + mi * 16 + g * 4 + j;
      float mx = -3.4e38f;
#pragma unroll
      for (int nt = 0; nt < 8; ++nt)
        if (nt <= ntmax) {
          const int col = nt * 16 + lr;
          const float val = sacc[mi][nt][j] * scl;
          if (col <= row) mx = fmaxf(mx, val);
        }
      mx = redmax16(mx);
      float sum = 0.f;
      const int rl = mi * 16 + g * 4 + j;
#pragma unroll
      for (int nt = 0; nt < 8; ++nt)
        if (nt <= ntmax) {
          const int col = nt * 16 + lr;
          const float val = sacc[mi][nt][j] * scl;
          const float pv = (col <= row) ? __expf(val - mx) : 0.f;
          sum += pv;
          const int chunk = (2 * nt + (lr >> 3)) ^ (rl & 7);
          pw[rl * 128 + chunk * 8 + (lr & 7)] = bf16c(pv);
        }
      sum = red16(sum);
      rv[mi][j] = 1.f / sum;
    }
  }
  // PV
  f32x4 oacc[2][2];
#pragma unroll
  for (int mi = 0; mi < 2; ++mi)
#pragma unroll
    for (int nt = 0; nt < 2; ++nt) oacc[mi][nt] = {0.f, 0.f, 0.f, 0.f};
#pragma unroll
  for (int kt = 0; kt < 4; ++kt)
    if (kt <= w) {
      bf16x8 pa[2], va[2];
#pragma unroll
      for (int mi = 0; mi < 2; ++mi) {
        const int rl = mi * 16 + lr;
        const int chunk = (4 * kt + g) ^ (rl & 7);
        pa[mi] = *reinterpret_cast<const bf16x8*>(&pw[rl * 128 + chunk * 8]);
      }
#pragma unroll
      for (int nt = 0; nt < 2; ++nt) {
        const int d = nt * 16 + lr;
        const int chunk = (4 * kt + g) ^ (d & 7);
        va[nt] = *reinterpret_cast<const bf16x8*>(&Vt[d * 128 + chunk * 8]);
      }
#pragma unroll
      for (int mi = 0; mi < 2; ++mi)
#pragma unroll
        for (int nt = 0; nt < 2; ++nt)
          oacc[mi][nt] = __builtin_amdgcn_mfma_f32_16x16x32_bf16(pa[mi], va[nt], oacc[mi][nt], 0, 0, 0);
    }
  // write y
#pragma unroll
  for (int mi = 0; mi < 2; ++mi)
#pragma unroll
    for (int nt = 0; nt < 2; ++nt)
#pragma unroll
      for (int j = 0; j < 4; ++j) {
        const int row = w * 32 + mi * 16 + g * 4 + j;
        y[((size_t)b * 128 + row) * 128 + h * 32 + nt * 16 + lr] = oacc[mi][nt][j] * rv[mi][j];
      }
}

// ---------------------------------------------------------------------------
// mhc combine; emits inv-rms of produced token.
// ---------------------------------------------------------------------------
__global__ __launch_bounds__(128) void mhc_combine(
    const float* __restrict__ xst, const float* __restrict__ hres,
    const float* __restrict__ hps, const float* __restrict__ yv,
    float* __restrict__ out, float* __restrict__ invout)
{
  const size_t i = blockIdx.x;
  const int c = threadIdx.x;
  __shared__ float H[16];
  __shared__ float g;
  __shared__ float part[2];
  if (c < 16) H[c] = hres[i * 16 + c];
  if (c == 16) g = hps[i];
  __syncthreads();
  const float x0 = xst[i * 512 + c];
  const float x1 = xst[i * 512 + 128 + c];
  const float x2 = xst[i * 512 + 256 + c];
  const float x3 = xst[i * 512 + 384 + c];
  const float yb = g * yv[i * 128 + c];
  const float o0 = H[0]  * x0 + H[1]  * x1 + H[2]  * x2 + H[3]  * x3 + yb;
  const float o1 = H[4]  * x0 + H[5]  * x1 + H[6]  * x2 + H[7]  * x3 + yb;
  const float o2 = H[8]  * x0 + H[9]  * x1 + H[10] * x2 + H[11] * x3 + yb;
  const float o3 = H[12] * x0 + H[13] * x1 + H[14] * x2 + H[15] * x3 + yb;
  out[i * 512 +       c] = o0;
  out[i * 512 + 128 + c] = o1;
  out[i * 512 + 256 + c] = o2;
  out[i * 512 + 384 + c] = o3;
  float ssq = o0 * o0 + o1 * o1 + o2 * o2 + o3 * o3;
  ssq = red64(ssq);
  if ((c & 63) == 0) part[c >> 6] = ssq;
  __syncthreads();
  if (c == 0) invout[i] = rsqrtf((part[0] + part[1]) * (1.f / 512.f) + EPSF);
}

// ---------------------------------------------------------------------------
extern "C" void kernel_launch(void* const* d_in, const int* in_sizes, int n_in,
                              void* d_out, int out_size, void* d_ws, size_t ws_size,
                              hipStream_t stream)
{
  const float* x        = (const float*)d_in[0];
  const int*   ids      = (const int*)d_in[1];
  const int*   mults    = (const int*)d_in[2];
  const float* table    = (const float*)d_in[3];
  const float* val_w    = (const float*)d_in[4];
  const float* val_b    = (const float*)d_in[5];
  const float* key_w    = (const float*)d_in[6];
  const float* key_b    = (const float*)d_in[7];
  const float* nq_w     = (const float*)d_in[8];
  const float* nk_w     = (const float*)d_in[9];
  const float* conv_w   = (const float*)d_in[10];
  const float* cnw      = (const float*)d_in[11];
  const float* a_coef   = (const float*)d_in[12];
  const float* a_pre_w  = (const float*)d_in[13];
  const float* a_pre_b  = (const float*)d_in[14];
  const float* a_post_w = (const float*)d_in[15];
  const float* a_post_b = (const float*)d_in[16];
  const float* a_res_w  = (const float*)d_in[17];
  const float* a_res_b  = (const float*)d_in[18];
  const float* a_apre   = (const float*)d_in[19];
  const float* a_apost  = (const float*)d_in[20];
  const float* a_ares   = (const float*)d_in[21];
  const float* a_ln_w   = (const float*)d_in[22];
  const float* qkv_w    = (const float*)d_in[23];
  const float* qkv_b    = (const float*)d_in[24];
  const float* proj_w   = (const float*)d_in[25];
  const float* proj_b   = (const float*)d_in[26];
  const float* m_coef   = (const float*)d_in[27];
  const float* m_pre_w  = (const float*)d_in[28];
  const float* m_pre_b  = (const float*)d_in[29];
  const float* m_post_w = (const float*)d_in[30];
  const float* m_post_b = (const float*)d_in[31];
  const float* m_res_w  = (const float*)d_in[32];
  const float* m_res_b  = (const float*)d_in[33];
  const float* m_apre   = (const float*)d_in[34];
  const float* m_apost  = (const float*)d_in[35];
  const float* m_ares   = (const float*)d_in[36];
  const float* m_ln_w   = (const float*)d_in[37];
  const float* mlp_w1   = (const float*)d_in[38];
  const float* mlp_b1   = (const float*)d_in[39];
  const float* mlp_w2   = (const float*)d_in[40];
  const float* mlp_b2   = (const float*)d_in[41];

  float* out = (float*)d_out;
  float* ws  = (float*)d_ws;
  float* vbase = ws;                        // BT*128
  float* kraw  = vbase + (size_t)BT * 128;  // BT*512 (k_raw -> qkv -> x2)
  float* gates = kraw  + (size_t)BT * 512;  // BT*4
  float* afac  = gates + (size_t)BT * 4;    // BT*4
  float* xa    = afac  + (size_t)BT * 4;    // BT*128
  float* y1    = xa    + (size_t)BT * 128;  // BT*128 (proj24 overlay / attn out)
  float* y2    = y1    + (size_t)BT * 128;  // BT*128
  float* hresb = y2    + (size_t)BT * 128;  // BT*16
  float* hpsb  = hresb + (size_t)BT * 16;   // BT
  float* inv1  = hpsb  + (size_t)BT;        // BT
  float* inv2  = inv1  + (size_t)BT;        // BT
  float* bpk_a = inv2  + (size_t)BT;        // 32
  float* bpk_m = bpk_a + 32;                // 32
  short* wt_qkv  = (short*)(bpk_m + 32);    // 384*128
  short* wt_proj = wt_qkv  + 49152;         // 128*128
  short* wt_mlp1 = wt_proj + 16384;         // 512*128
  short* wt_mlp2 = wt_mlp1 + 65536;         // 128*512
  short* wt_eng  = wt_mlp2 + 65536;         // 640*256
  short* wpk_a   = wt_eng  + 163840;        // 32*512
  short* wpk_m   = wpk_a   + 16384;         // 32*512
  float* proj24  = y1;                      // BT*32 overlay

  prep<<<1537, 256, 0, stream>>>(qkv_w, proj_w, mlp_w1, mlp_w2, val_w, key_w,
                                 a_res_w, a_pre_w, a_post_w, m_res_w, m_pre_w, m_post_w,
                                 a_res_b, a_pre_b, a_post_b, m_res_b, m_pre_b, m_post_b,
                                 wt_qkv, wt_proj, wt_mlp1, wt_mlp2, wt_eng,
                                 wpk_a, wpk_m, bpk_a, bpk_m);

  // ---- engram ----
  eng_mgemm<<<dim3(BT / 128, 5), 256, 0, stream>>>(ids, mults, table, val_b, wt_eng,
                                                   vbase, kraw);
  eng_gate<<<BT / 4, 256, 0, stream>>>(kraw, x, vbase, key_b, nk_w, nq_w, gates, afac);
  eng_conv<<<BT, 256, 0, stream>>>(x, vbase, gates, afac, conv_w, cnw, out, inv1);

  // ---- mhc (attention) ----
  mgemm32<<<BT / 128, 256, 0, stream>>>(out, 512, wpk_a, bpk_a, proj24, 512, inv1, a_coef);
  mhc_sink<<<BT / 4, 256, 0, stream>>>(proj24, out, a_apre, a_apost, a_ares, a_ln_w,
                                       xa, hresb, hpsb);
  mgemm<0, false><<<dim3(BT / 128, 3), 256, 0, stream>>>(xa, 128, wt_qkv, qkv_b,
                                                         kraw, 384, 128, nullptr, nullptr);
  attn_mfma<<<1024, 256, 0, stream>>>(kraw, y1);
  mgemm<0, false><<<dim3(BT / 128, 1), 256, 0, stream>>>(y1, 128, wt_proj, proj_b,
                                                         y2, 128, 128, nullptr, nullptr);
  mhc_combine<<<BT, 128, 0, stream>>>(out, hresb, hpsb, y2, kraw, inv2);

  // ---- mhc (mlp) ----
  mgemm32<<<BT / 128, 256, 0, stream>>>(kraw, 512, wpk_m, bpk_m, proj24, 512, inv2, m_coef);
  mhc_sink<<<BT / 4, 256, 0, stream>>>(proj24, kraw, m_apre, m_apost, m_ares, m_ln_w,
                                       xa, hresb, hpsb);
  mgemm<1, false><<<dim3(BT / 128, 4), 256, 0, stream>>>(xa, 128, wt_mlp1, mlp_b1,
                                                         out, 512, 128, nullptr, nullptr);
  mgemm<0, false><<<dim3(BT / 128, 1), 256, 0, stream>>>(out, 512, wt_mlp2, mlp_b2,
                                                         y2, 128, 512, nullptr, nullptr);
  mhc_combine<<<BT, 128, 0, stream>>>(kraw, hresb, hpsb, y2, out, inv1);

  (void)in_sizes; (void)n_in; (void)out_size; (void)ws_size;
}